// Round 15
// baseline (296.112 us; speedup 1.0000x reference)
//
#include <hip/hip_runtime.h>
#include <cfloat>
#include <cmath>

// ---------------------------------------------------------------------------
// GNN message passing — fp16 MFMA, round 15.
//  R15 change (single, structural): k_mlp block 512->256 threads (32 nodes).
//  r14 evidence: k_mlp pinned at 71.5us, occ 47%, VALU 39%, HBM 10% ->
//  latency-bound with too few independent waves. 256-thr blocks: LDS
//  17.9KB -> 8 blocks/CU (32 waves, 100% theoretical), 3126 blocks for finer
//  balance, 2x independent gather streams per CU. Work re-partitioned over
//  4 waves (GEMM1: 32 chunk-cols/wave; GEMM2: acc2[2][2]; GEMM3: waves 0-1).
//  WRITE_SIZE ~6250KB is the spill sentinel.
// MFMA mapping (verified r3-r14): D=A*B, A=W^T[nout][k], B=H[node][k]; D:
// col=lane&15=node, row=(lane>>4)*4+reg=nout.
// ---------------------------------------------------------------------------

typedef _Float16 half_t;
typedef _Float16 half8 __attribute__((ext_vector_type(8)));
typedef _Float16 half4_t __attribute__((ext_vector_type(4)));
typedef _Float16 half2_t __attribute__((ext_vector_type(2)));
typedef float f32x4 __attribute__((ext_vector_type(4)));

#define NPB 512       // nodes per bin (power of 2: bin = dst>>9)
#define BIN_CAP 9216  // slots per bin; mean 8163, sd ~90 -> +11.7 sigma
#define IDXCAP 2176   // LDS idx slots per k_mlp block (mean 512, +73 sigma)

__device__ __forceinline__ float fast_tanh(float x) {
    float e = __builtin_amdgcn_exp2f(x * 2.8853900817779268f);
    return 1.0f - 2.0f * __builtin_amdgcn_rcpf(1.0f + e);
}

__device__ __forceinline__ half_t cvt_clamp(float v) {
    return (half_t)fminf(fmaxf(v, -60000.f), 60000.f);
}

__device__ __forceinline__ half2_t h2shfl_xor(half2_t v, int mask) {
    int i = __builtin_bit_cast(int, v);
    i = __shfl_xor(i, mask);
    return __builtin_bit_cast(half2_t, i);
}

// ---------------- phase A: bin edges + pack fp16 ew (coalesced staging) ----------------
__global__ __launch_bounds__(256) void k_binA(
    const int* __restrict__ dst, const int* __restrict__ src,
    const float4* __restrict__ ew4,
    int* __restrict__ binCnt, int4* __restrict__ staged, int E, int nbins) {
    __shared__ int cnt[256], base[256], cur[256];
    int t = threadIdx.x;
    cnt[t] = 0;
    cur[t] = 0;
    __syncthreads();
    int e0 = blockIdx.x * 8192;
#pragma unroll 4
    for (int i = 0; i < 32; ++i) {
        int e = e0 + i * 256 + t;
        if (e < E) atomicAdd(&cnt[dst[e] >> 9], 1);
    }
    __syncthreads();
    if (t < nbins && cnt[t] > 0) base[t] = atomicAdd(&binCnt[t], cnt[t]);
    __syncthreads();
#pragma unroll 4
    for (int i = 0; i < 32; ++i) {
        int e = e0 + i * 256 + t;
        if (e < E) {
            int d = dst[e];
            int b = d >> 9;
            int j = base[b] + atomicAdd(&cur[b], 1);
            if (j < BIN_CAP) {
                float4 w = ew4[e];   // coalesced here (e sequential)
                half2_t lo = {(half_t)w.x, (half_t)w.y};
                half2_t hi = {(half_t)w.z, (half_t)w.w};
                staged[(size_t)b * BIN_CAP + j] =
                    make_int4(src[e], d & (NPB - 1),
                              __builtin_bit_cast(int, lo),
                              __builtin_bit_cast(int, hi));
            }
        }
    }
}

// ---------------- bin-count exclusive scan (nbins <= 256) ----------------
__global__ void k_scanN(const int* __restrict__ binCnt, int* __restrict__ binStart,
                        int* __restrict__ row_start, int nbins, int n, int E) {
    __shared__ int sh[256];
    int t = threadIdx.x;
    int v = (t < nbins) ? binCnt[t] : 0;
    sh[t] = v;
    __syncthreads();
    for (int s = 1; s < 256; s <<= 1) {
        int u = (t >= s) ? sh[t - s] : 0;
        __syncthreads();
        sh[t] += u;
        __syncthreads();
    }
    if (t < nbins) binStart[t] = sh[t] - v;
    if (t == 0) row_start[n] = E;
}

// ---------------- phase B: per-bin CSR; stats via per-node walk of sew ----------------
__global__ __launch_bounds__(512) void k_binB(
    const int* __restrict__ binCnt, const int* __restrict__ binStart,
    const int4* __restrict__ staged, const float* __restrict__ x,
    int* __restrict__ row_start, int* __restrict__ snbr, int2* __restrict__ sew,
    half_t* __restrict__ reps, int n) {
    __shared__ int deg[NPB], cur[NPB], rsl[NPB];
    int t = threadIdx.x;
    int bin = blockIdx.x;
    int cntE = min(binCnt[bin], BIN_CAP);
    int pbase = binStart[bin];
    const int4* st = staged + (size_t)bin * BIN_CAP;

    deg[t] = 0;
    cur[t] = 0;
    __syncthreads();

    // pass 1: degree count only (1 LDS atomic/edge)
    for (int i = t; i < cntE; i += 512)
        atomicAdd(&deg[st[i].y], 1);
    __syncthreads();

    int own = deg[t];
    for (int s = 1; s < NPB; s <<= 1) {   // inclusive Hillis-Steele scan
        int u = (t >= s) ? deg[t - s] : 0;
        __syncthreads();
        deg[t] += u;
        __syncthreads();
    }
    int excl = deg[t] - own;
    rsl[t] = pbase + excl;
    int node = bin * NPB + t;
    if (node < n) row_start[node] = pbase + excl;
    __syncthreads();

    // pass 2: scatter snbr + packed ew (1 LDS atomic/edge)
    for (int i = t; i < cntE; i += 512) {
        int4 v = st[i];
        int p = rsl[v.y] + atomicAdd(&cur[v.y], 1);
        snbr[p] = v.x;
        sew[p] = make_int2(v.z, v.w);
    }
    __syncthreads();   // sew visible block-wide (same-block L2)

    // pass 3: per-node stats via sequential walk (L2-hot window, no atomics)
    if (node < n) {
        int base = rsl[t];
        float s0 = 0.f, s1 = 0.f, s2 = 0.f, s3 = 0.f;
        half2_t mxlo = {(half_t)-65504.f, (half_t)-65504.f};
        half2_t mxhi = mxlo;
        half2_t mnlo = {(half_t)65504.f, (half_t)65504.f};
        half2_t mnhi = mnlo;
#pragma unroll 2
        for (int k = 0; k < own; ++k) {
            int2 e = sew[base + k];
            half2_t lo = __builtin_bit_cast(half2_t, e.x);
            half2_t hi = __builtin_bit_cast(half2_t, e.y);
            s0 += (float)lo[0];
            s1 += (float)lo[1];
            s2 += (float)hi[0];
            s3 += (float)hi[1];
            mxlo = __builtin_elementwise_max(mxlo, lo);
            mxhi = __builtin_elementwise_max(mxhi, hi);
            mnlo = __builtin_elementwise_min(mnlo, lo);
            mnhi = __builtin_elementwise_min(mnhi, hi);
        }
        float cnt = fmaxf((float)own, 1.0f);
        float rc = __builtin_amdgcn_rcpf(cnt);
        float mx0, mx1, mx2, mx3, mn0, mn1, mn2, mn3;
        if (own == 0) {
            mx0 = mx1 = mx2 = mx3 = -FLT_MAX;
            mn0 = mn1 = mn2 = mn3 = FLT_MAX;
        } else {
            mx0 = (float)mxlo[0]; mx1 = (float)mxlo[1];
            mx2 = (float)mxhi[0]; mx3 = (float)mxhi[1];
            mn0 = (float)mnlo[0]; mn1 = (float)mnlo[1];
            mn2 = (float)mnhi[0]; mn3 = (float)mnhi[1];
        }
        const float4* x4 = reinterpret_cast<const float4*>(x);
        float4 x0 = x4[node * 2 + 0], x1 = x4[node * 2 + 1];
        half_t* o = &reps[(size_t)node * 32];
        half8 c0 = {cvt_clamp(x0.x), cvt_clamp(x0.y), cvt_clamp(x0.z), cvt_clamp(x0.w),
                    cvt_clamp(x1.x), cvt_clamp(x1.y), cvt_clamp(x1.z), cvt_clamp(x1.w)};
        half8 c1 = {cvt_clamp(s0 * rc), cvt_clamp(s1 * rc), cvt_clamp(s2 * rc), cvt_clamp(s3 * rc),
                    cvt_clamp(mx0), cvt_clamp(mx1), cvt_clamp(mx2), cvt_clamp(mx3)};
        half8 c2 = {cvt_clamp(mn0), cvt_clamp(mn1), cvt_clamp(mn2), cvt_clamp(mn3),
                    cvt_clamp(s0), cvt_clamp(s1), cvt_clamp(s2), cvt_clamp(s3)};
        half8 c3 = {(half_t)0.f, (half_t)0.f, (half_t)0.f, (half_t)0.f,
                    (half_t)0.f, (half_t)0.f, (half_t)0.f, (half_t)0.f};
        *(half8*)&o[0] = c0;
        *(half8*)&o[8] = c1;
        *(half8*)&o[16] = c2;
        *(half8*)&o[24] = c3;
    }
}

// ---------------- weight prep: fp32 [k][n] -> fp16 [n][k] ----------------
__global__ void k_wprep(const float* __restrict__ Wu1, const float* __restrict__ Wu2,
                        const float* __restrict__ Wu3, half_t* __restrict__ Wt1,
                        half_t* __restrict__ Wt2, half_t* __restrict__ Wt3) {
    int i = blockIdx.x * 256 + threadIdx.x;
    if (i < 32768) {
        int nrow = i >> 7, k = i & 127;
        Wt1[i] = (half_t)Wu1[k * 256 + nrow];
    } else if (i < 65536) {
        int j = i - 32768;
        int nrow = j >> 8, k = j & 255;
        Wt2[j] = (half_t)Wu2[k * 128 + nrow];
    } else if (i < 69632) {
        int j = i - 65536;
        int nrow = j >> 7, k = j & 127;
        Wt3[j] = (half_t)Wu3[k * 32 + nrow];
    }
}

// ---------------- fused iter: 256 thr / 32 nodes; gather + split-K MLP + l2norm ----------------
// nlist == nullptr: node = node0 + slot (contiguous tile, sIdx staging).
// nlist != nullptr: node = nlist[node0 + slot] (sparse list; direct snbr reads).
#define MFMA16(a, b, c) __builtin_amdgcn_mfma_f32_16x16x32_f16((a), (b), (c), 0, 0, 0)

__global__ __launch_bounds__(256, 6) void k_mlp(
    const half_t* __restrict__ reps_in,
    const int* __restrict__ row_start, const int* __restrict__ snbr,
    const int* __restrict__ nlist, int nlen,
    const half_t* __restrict__ Wt1, const half_t* __restrict__ Wt2,
    const half_t* __restrict__ Wt3,
    const float* __restrict__ bu1, const float* __restrict__ bu2,
    const float* __restrict__ bu3,
    half_t* __restrict__ reps_out, int n) {
    __shared__ half_t sH[32 * 136];     // H[32][128]; later h2[32][128]
    __shared__ half_t sh1c[32 * 136];   // idx stage, then h1 chunk [32][128]
    __shared__ int sDeg[32], sPerm[32], sNode[32];
    int* sIdx = (int*)sh1c;             // 2176 int slots

    const int tid = threadIdx.x;
    const int w   = tid >> 6;           // wave 0..3
    const int l15 = tid & 15;
    const int lk  = (tid & 63) >> 4;    // k-group 0..3
    const int node0 = blockIdx.x * 32;

    // ---- node table + degrees ----
    if (tid < 32) {
        int node;
        if (nlist) {
            int li = node0 + tid;
            node = (li < nlen) ? nlist[li] : -1;
        } else {
            node = node0 + tid;
        }
        if ((unsigned)node >= (unsigned)n) node = -1;
        sNode[tid] = node;
        sDeg[tid] = (node >= 0) ? (row_start[node + 1] - row_start[node]) : 0;
    }
    // ---- idx stage (identity path only): contiguous CSR -> coalesced burst ----
    const int nodeEnd = min(node0 + 32, n);
    int d0blk = 0;
    bool lds_ok = false;
    if (!nlist && node0 < n) {
        d0blk = row_start[node0];
        int ecnt = row_start[nodeEnd] - d0blk;
        lds_ok = (ecnt <= IDXCAP);
        if (lds_ok) {
            for (int i = tid; i < ecnt; i += 256)
                sIdx[i] = __builtin_nontemporal_load(&snbr[d0blk + i]);
        }
    }
    __syncthreads();
    // rank nodes by degree (desc, index tie-break) -> bijective perm
    if (tid < 32) {
        int dg = sDeg[tid];
        int rank = 0;
#pragma unroll
        for (int j = 0; j < 32; ++j) {
            int dj = sDeg[j];
            rank += (dj > dg) || (dj == dg && j < tid);
        }
        sPerm[rank] = tid;
    }
    __syncthreads();

    // ---- gather: 16 subgroups of 16 lanes; lane=(nb,ch); 16 edges/iter ----
    {
        const int sg = tid >> 4;   // 0..15
        const int l  = tid & 15;
        const int nb = l >> 2;
        const int ch = l & 3;

        for (int i = 0; i < 2; ++i) {
            int nl = sPerm[i * 16 + sg];
            int node = sNode[nl];
            float s[8];
            half2_t mx2[4], mn2[4];
#pragma unroll
            for (int f = 0; f < 8; ++f) s[f] = 0.f;
#pragma unroll
            for (int f = 0; f < 4; ++f) {
                mx2[f] = (half2_t){(half_t)-65504.f, (half_t)-65504.f};
                mn2[f] = (half2_t){(half_t)65504.f, (half_t)65504.f};
            }
            int d0 = 0, d1 = 0;
            if (node >= 0) { d0 = row_start[node]; d1 = row_start[node + 1]; }

            for (int e = d0; e < d1; e += 16) {
                int e0 = e + nb, e1 = e + 4 + nb, e2 = e + 8 + nb, e3 = e + 12 + nb;
                float m0 = (e0 < d1) ? 1.f : 0.f;
                float m1 = (e1 < d1) ? 1.f : 0.f;
                float m2 = (e2 < d1) ? 1.f : 0.f;
                float m3 = (e3 < d1) ? 1.f : 0.f;
                int ii0, ii1, ii2, ii3;
                if (lds_ok) {
                    ii0 = sIdx[min(e0, d1 - 1) - d0blk];
                    ii1 = sIdx[min(e1, d1 - 1) - d0blk];
                    ii2 = sIdx[min(e2, d1 - 1) - d0blk];
                    ii3 = sIdx[min(e3, d1 - 1) - d0blk];
                } else {
                    ii0 = snbr[min(e0, d1 - 1)];
                    ii1 = snbr[min(e1, d1 - 1)];
                    ii2 = snbr[min(e2, d1 - 1)];
                    ii3 = snbr[min(e3, d1 - 1)];
                }
                half8 r0 = *(const half8*)&reps_in[(size_t)ii0 * 32 + ch * 8];
                half8 r1 = *(const half8*)&reps_in[(size_t)ii1 * 32 + ch * 8];
                half8 r2 = *(const half8*)&reps_in[(size_t)ii2 * 32 + ch * 8];
                half8 r3 = *(const half8*)&reps_in[(size_t)ii3 * 32 + ch * 8];
#pragma unroll
                for (int f = 0; f < 4; ++f) {
                    half2_t a0 = (half2_t){r0[2 * f], r0[2 * f + 1]};
                    half2_t a1 = (half2_t){r1[2 * f], r1[2 * f + 1]};
                    half2_t a2 = (half2_t){r2[2 * f], r2[2 * f + 1]};
                    half2_t a3 = (half2_t){r3[2 * f], r3[2 * f + 1]};
                    mx2[f] = __builtin_elementwise_max(
                        __builtin_elementwise_max(mx2[f], a0),
                        __builtin_elementwise_max(a1,
                            __builtin_elementwise_max(a2, a3)));
                    mn2[f] = __builtin_elementwise_min(
                        __builtin_elementwise_min(mn2[f], a0),
                        __builtin_elementwise_min(a1,
                            __builtin_elementwise_min(a2, a3)));
                }
#pragma unroll
                for (int f = 0; f < 8; ++f) {
                    s[f] = fmaf((float)r0[f], m0, s[f]);
                    s[f] = fmaf((float)r1[f], m1, s[f]);
                    s[f] = fmaf((float)r2[f], m2, s[f]);
                    s[f] = fmaf((float)r3[f], m3, s[f]);
                }
            }
            // reduce across the 4 nb slots (xor strides 4, 8 inside subgroup)
#pragma unroll
            for (int f = 0; f < 8; ++f) {
                s[f] += __shfl_xor(s[f], 4);
                s[f] += __shfl_xor(s[f], 8);
            }
#pragma unroll
            for (int f = 0; f < 4; ++f) {
                mx2[f] = __builtin_elementwise_max(mx2[f], h2shfl_xor(mx2[f], 4));
                mx2[f] = __builtin_elementwise_max(mx2[f], h2shfl_xor(mx2[f], 8));
                mn2[f] = __builtin_elementwise_min(mn2[f], h2shfl_xor(mn2[f], 4));
                mn2[f] = __builtin_elementwise_min(mn2[f], h2shfl_xor(mn2[f], 8));
            }
            float cnt = fmaxf((float)(d1 - d0), 1.f);
            half8 o;
            if (nb == 0) {
                if (node >= 0) {
                    o = *(const half8*)&reps_in[(size_t)node * 32 + ch * 8];
                } else {
#pragma unroll
                    for (int f = 0; f < 8; ++f) o[f] = (half_t)0.f;
                }
            } else if (nb == 1) {
                float rc = __builtin_amdgcn_rcpf(cnt);
#pragma unroll
                for (int f = 0; f < 8; ++f) o[f] = cvt_clamp(s[f] * rc);
            } else if (nb == 2) {
#pragma unroll
                for (int f = 0; f < 4; ++f) {
                    o[2 * f]     = cvt_clamp((float)mx2[f][0]);
                    o[2 * f + 1] = cvt_clamp((float)mx2[f][1]);
                }
            } else {
#pragma unroll
                for (int f = 0; f < 4; ++f) {
                    o[2 * f]     = cvt_clamp((float)mn2[f][0]);
                    o[2 * f + 1] = cvt_clamp((float)mn2[f][1]);
                }
            }
            *(half8*)&sH[nl * 136 + l * 8] = o;
        }
    }
    __syncthreads();   // gather done; sIdx dead -> sh1c reusable

    // ---- split-K: 2 chunks of {GEMM1 128 cols -> GEMM2 partial} ----
    // GEMM1: wave w owns chunk cols [w*32, w*32+32). GEMM2: out cols [w*32,+32).
    f32x4 acc2[2][2] = {{{0.f, 0.f, 0.f, 0.f}, {0.f, 0.f, 0.f, 0.f}},
                        {{0.f, 0.f, 0.f, 0.f}, {0.f, 0.f, 0.f, 0.f}}};
#pragma unroll
    for (int c = 0; c < 2; ++c) {
        // GEMM1 chunk c
        {
            half8 a0[4], a1[4];
#pragma unroll
            for (int ks = 0; ks < 4; ++ks) {
                a0[ks] = *(const half8*)&Wt1[(c * 128 + w * 32 + l15) * 128 + ks * 32 + lk * 8];
                a1[ks] = *(const half8*)&Wt1[(c * 128 + w * 32 + 16 + l15) * 128 + ks * 32 + lk * 8];
            }
            f32x4 bv0 = *(const f32x4*)&bu1[c * 128 + w * 32 + lk * 4];
            f32x4 bv1 = *(const f32x4*)&bu1[c * 128 + w * 32 + 16 + lk * 4];
#pragma unroll
            for (int nt = 0; nt < 2; ++nt) {
                const half_t* hrow = &sH[(nt * 16 + l15) * 136 + lk * 8];
                half8 b0 = *(const half8*)&hrow[0];
                half8 b1 = *(const half8*)&hrow[32];
                half8 b2 = *(const half8*)&hrow[64];
                half8 b3 = *(const half8*)&hrow[96];
                f32x4 acc0 = {0.f, 0.f, 0.f, 0.f}, acc1 = {0.f, 0.f, 0.f, 0.f};
                acc0 = MFMA16(a0[0], b0, acc0);
                acc0 = MFMA16(a0[1], b1, acc0);
                acc0 = MFMA16(a0[2], b2, acc0);
                acc0 = MFMA16(a0[3], b3, acc0);
                acc1 = MFMA16(a1[0], b0, acc1);
                acc1 = MFMA16(a1[1], b1, acc1);
                acc1 = MFMA16(a1[2], b2, acc1);
                acc1 = MFMA16(a1[3], b3, acc1);
                int nodeLoc = nt * 16 + l15;
                half4_t o0, o1;
#pragma unroll
                for (int r = 0; r < 4; ++r) {
                    o0[r] = (half_t)fast_tanh(acc0[r] + bv0[r]);
                    o1[r] = (half_t)fast_tanh(acc1[r] + bv1[r]);
                }
                *(half4_t*)&sh1c[nodeLoc * 136 + w * 32 + lk * 4] = o0;
                *(half4_t*)&sh1c[nodeLoc * 136 + w * 32 + 16 + lk * 4] = o1;
            }
        }
        __syncthreads();   // h1 chunk ready
        // GEMM2 partial: k in [c*128, c*128+128)
        {
            half8 aA[4], aB[4];
#pragma unroll
            for (int ks = 0; ks < 4; ++ks) {
                aA[ks] = *(const half8*)&Wt2[(w * 32 + l15) * 256 + c * 128 + ks * 32 + lk * 8];
                aB[ks] = *(const half8*)&Wt2[(w * 32 + 16 + l15) * 256 + c * 128 + ks * 32 + lk * 8];
            }
#pragma unroll
            for (int nt = 0; nt < 2; ++nt) {
#pragma unroll
                for (int ks = 0; ks < 4; ++ks) {
                    half8 b = *(const half8*)&sh1c[(nt * 16 + l15) * 136 + ks * 32 + lk * 8];
                    acc2[0][nt] = MFMA16(aA[ks], b, acc2[0][nt]);
                    acc2[1][nt] = MFMA16(aB[ks], b, acc2[1][nt]);
                }
            }
        }
        __syncthreads();   // chunk reads done before overwrite / sH overlay
    }

    // ---- h2 = tanh(acc2 + b2) -> overlay into sH (dead after GEMM1) ----
    {
        f32x4 bv0 = *(const f32x4*)&bu2[w * 32 + lk * 4];
        f32x4 bv1 = *(const f32x4*)&bu2[w * 32 + 16 + lk * 4];
#pragma unroll
        for (int nt = 0; nt < 2; ++nt) {
            half4_t o0, o1;
#pragma unroll
            for (int r = 0; r < 4; ++r) {
                o0[r] = (half_t)fast_tanh(acc2[0][nt][r] + bv0[r]);
                o1[r] = (half_t)fast_tanh(acc2[1][nt][r] + bv1[r]);
            }
            *(half4_t*)&sH[(nt * 16 + l15) * 136 + w * 32 + lk * 4] = o0;
            *(half4_t*)&sH[(nt * 16 + l15) * 136 + w * 32 + 16 + lk * 4] = o1;
        }
    }
    __syncthreads();

    // ---- GEMM3 + l2norm: waves 0..1, wave w owns nodes [w*16,(w+1)*16) ----
    if (w < 2) {
        half8 a0[4], a1[4], b[4];
#pragma unroll
        for (int ks = 0; ks < 4; ++ks) {
            a0[ks] = *(const half8*)&Wt3[l15 * 128 + ks * 32 + lk * 8];
            a1[ks] = *(const half8*)&Wt3[(16 + l15) * 128 + ks * 32 + lk * 8];
            b[ks]  = *(const half8*)&sH[(w * 16 + l15) * 136 + ks * 32 + lk * 8];
        }
        f32x4 acc0 = {0.f, 0.f, 0.f, 0.f}, acc1 = {0.f, 0.f, 0.f, 0.f};
#pragma unroll
        for (int ks = 0; ks < 4; ++ks) {
            acc0 = MFMA16(a0[ks], b[ks], acc0);
            acc1 = MFMA16(a1[ks], b[ks], acc1);
        }
        f32x4 bv0 = *(const f32x4*)&bu3[lk * 4];
        f32x4 bv1 = *(const f32x4*)&bu3[16 + lk * 4];
        float v0[4], v1[4];
        float ss = 0.f;
#pragma unroll
        for (int r = 0; r < 4; ++r) {
            v0[r] = fast_tanh(acc0[r] + bv0[r]);
            v1[r] = fast_tanh(acc1[r] + bv1[r]);
            ss += v0[r] * v0[r] + v1[r] * v1[r];
        }
        ss += __shfl_xor(ss, 16);
        ss += __shfl_xor(ss, 32);
        float sc = rsqrtf(fmaxf(ss, 1e-12f));
        int node = sNode[w * 16 + l15];
        if (node >= 0) {
            half4_t o0, o1;
#pragma unroll
            for (int r = 0; r < 4; ++r) {
                o0[r] = (half_t)(v0[r] * sc);
                o1[r] = (half_t)(v1[r] * sc);
            }
            *(half4_t*)&reps_out[(size_t)node * 32 + lk * 4] = o0;
            *(half4_t*)&reps_out[(size_t)node * 32 + 16 + lk * 4] = o1;
        }
    }
}

// ---------------- readout: gather generators (nan->0), 32->64->32->1 ----------------
__global__ __launch_bounds__(256) void k_readout(
    const half_t* __restrict__ reps, const int* __restrict__ gen,
    const float* __restrict__ Wr1, const float* __restrict__ br1,
    const float* __restrict__ Wr2, const float* __restrict__ br2,
    const float* __restrict__ Wr3, const float* __restrict__ br3,
    float* __restrict__ out, int ngen) {
    __shared__ float sW1[32 * 64];
    __shared__ float sW2[64 * 32];
    __shared__ float sb1[64];
    __shared__ float sb2[32];
    __shared__ float sW3r[32];
    __shared__ float sb3;
    int tid = threadIdx.x;
    for (int i = tid; i < 2048; i += 256) sW1[i] = Wr1[i];
    for (int i = tid; i < 2048; i += 256) sW2[i] = Wr2[i];
    if (tid < 64) sb1[tid] = br1[tid];
    if (tid < 32) sb2[tid] = br2[tid];
    if (tid < 32) sW3r[tid] = Wr3[tid];
    if (tid == 0) sb3 = br3[0];
    __syncthreads();
    int ig = blockIdx.x * 256 + tid;
    if (ig >= ngen) return;
    int node = gen[ig];
    float g[32];
#pragma unroll
    for (int q = 0; q < 4; ++q) {
        half8 v = *(const half8*)&reps[(size_t)node * 32 + q * 8];
#pragma unroll
        for (int r = 0; r < 8; ++r) {
            float f = (float)v[r];
            g[q * 8 + r] = (f != f) ? 0.f : f;
        }
    }
    float a[64];
#pragma unroll
    for (int o = 0; o < 64; ++o) {
        float acc = sb1[o];
#pragma unroll
        for (int k = 0; k < 32; ++k) acc = fmaf(g[k], sW1[k * 64 + o], acc);
        a[o] = fast_tanh(acc);
    }
    float b[32];
#pragma unroll
    for (int o = 0; o < 32; ++o) {
        float acc = sb2[o];
#pragma unroll
        for (int k = 0; k < 64; ++k) acc = fmaf(a[k], sW2[k * 32 + o], acc);
        b[o] = fast_tanh(acc);
    }
    float acc = sb3;
#pragma unroll
    for (int k = 0; k < 32; ++k) acc = fmaf(b[k], sW3r[k], acc);
    out[ig] = acc;
}

extern "C" void kernel_launch(void* const* d_in, const int* in_sizes, int n_in,
                              void* d_out, int out_size, void* d_ws, size_t ws_size,
                              hipStream_t stream) {
    const float* x   = (const float*)d_in[0];
    const float* ew  = (const float*)d_in[1];
    const float* Wu1 = (const float*)d_in[2];
    const float* bu1 = (const float*)d_in[3];
    const float* Wu2 = (const float*)d_in[4];
    const float* bu2 = (const float*)d_in[5];
    const float* Wu3 = (const float*)d_in[6];
    const float* bu3 = (const float*)d_in[7];
    const float* Wr1 = (const float*)d_in[8];
    const float* br1 = (const float*)d_in[9];
    const float* Wr2 = (const float*)d_in[10];
    const float* br2 = (const float*)d_in[11];
    const float* Wr3 = (const float*)d_in[12];
    const float* br3 = (const float*)d_in[13];
    const int* edges = (const int*)d_in[14];
    const int* gen   = (const int*)d_in[15];

    const int n    = in_sizes[0] / 8;
    const int E    = in_sizes[1] / 4;
    const int ngen = in_sizes[15];
    const int* dst = edges;      // node_idx (segment ids)
    const int* src = edges + E;  // nbr_idx (gather source)
    float* out = (float*)d_out;

    const int nblk  = (n + 31) / 32;
    const int npad  = nblk * 32;
    const int nbins = (n + NPB - 1) / NPB;

    // workspace layout (256B aligned slabs)
    char* ws = (char*)d_ws;
    size_t off = 0;
    auto alloc = [&](size_t bytes) -> char* {
        char* p = ws + off;
        off = (off + bytes + 255) & ~(size_t)255;
        return p;
    };
    int* row_start = (int*)alloc((size_t)(n + 1) * 4);
    int* binCnt    = (int*)alloc(256 * 4);
    int* binStart  = (int*)alloc(256 * 4);
    int* snbr      = (int*)alloc((size_t)E * 4);
    int2* sew      = (int2*)alloc((size_t)E * 8);   // CSR-ordered packed fp16 ew
    half_t* repsA  = (half_t*)alloc((size_t)npad * 32 * 2);
    half_t* repsB  = (half_t*)alloc((size_t)npad * 32 * 2);
    half_t* Wt1    = (half_t*)alloc(32768 * 2);
    half_t* Wt2    = (half_t*)alloc(32768 * 2);
    half_t* Wt3    = (half_t*)alloc(4096 * 2);
    int4* staged   = (int4*)alloc((size_t)nbins * BIN_CAP * 16);   // CSR build only

    // ---- CSR build (binned) + stats + reps ----
    hipMemsetAsync(binCnt, 0, 256 * 4, stream);
    int nblkA = (E + 8191) / 8192;
    k_binA<<<nblkA, 256, 0, stream>>>(dst, src, (const float4*)ew, binCnt, staged, E, nbins);
    k_scanN<<<1, 256, 0, stream>>>(binCnt, binStart, row_start, nbins, n, E);
    k_binB<<<nbins, 512, 0, stream>>>(binCnt, binStart, staged, x,
                                      row_start, snbr, sew, repsA, n);
    k_wprep<<<272, 256, 0, stream>>>(Wu1, Wu2, Wu3, Wt1, Wt2, Wt3);

    // it1, it2: full sweeps (identity mapping, sIdx staging)
    k_mlp<<<nblk, 256, 0, stream>>>(repsA, row_start, snbr, nullptr, 0,
                                    Wt1, Wt2, Wt3, bu1, bu2, bu3, repsB, n);
    k_mlp<<<nblk, 256, 0, stream>>>(repsB, row_start, snbr, nullptr, 0,
                                    Wt1, Wt2, Wt3, bu1, bu2, bu3, repsA, n);
    // it3: generator nodes only (readout consumes nothing else)
    int nblk3 = (ngen + 31) / 32;
    k_mlp<<<nblk3, 256, 0, stream>>>(repsA, row_start, snbr, gen, ngen,
                                     Wt1, Wt2, Wt3, bu1, bu2, bu3, repsB, n);

    k_readout<<<(ngen + 255) / 256, 256, 0, stream>>>(repsB, gen, Wr1, br1, Wr2, br2,
                                                      Wr3, br3, out, ngen);
}

// Round 16
// 261.779 us; speedup vs baseline: 1.1312x; 1.1312x over previous
//
#include <hip/hip_runtime.h>
#include <cfloat>
#include <cmath>

// ---------------------------------------------------------------------------
// GNN message passing — fp16 MFMA, round 16.
//  R16 = revert k_mlp to the r14 shape (512 thr / 64 nodes). r15's 256-thr
//  blocks regressed (71.5->88us): FETCH 51->74MB (halved weight reuse ->
//  doubled weight traffic) and WRITE 6250->37500KB (spill/write-allocate),
//  while occupancy only moved 47->50% — the latency bottleneck is NOT wave
//  count; 64-node tiles win on weight-fetch amortization.
//  All other kernels unchanged from r14/r15 (binned CSR with packed fp16 ew,
//  binB sequential-walk stats, it3 gen-only).
// MFMA mapping (verified r3-r14): D=A*B, A=W^T[nout][k], B=H[node][k]; D:
// col=lane&15=node, row=(lane>>4)*4+reg=nout.
// ---------------------------------------------------------------------------

typedef _Float16 half_t;
typedef _Float16 half8 __attribute__((ext_vector_type(8)));
typedef _Float16 half4_t __attribute__((ext_vector_type(4)));
typedef _Float16 half2_t __attribute__((ext_vector_type(2)));
typedef float f32x4 __attribute__((ext_vector_type(4)));

#define NPB 512       // nodes per bin (power of 2: bin = dst>>9)
#define BIN_CAP 9216  // slots per bin; mean 8163, sd ~90 -> +11.7 sigma
#define IDXCAP 4352   // LDS idx slots per k_mlp block (mean 1024)

__device__ __forceinline__ float fast_tanh(float x) {
    float e = __builtin_amdgcn_exp2f(x * 2.8853900817779268f);
    return 1.0f - 2.0f * __builtin_amdgcn_rcpf(1.0f + e);
}

__device__ __forceinline__ half_t cvt_clamp(float v) {
    return (half_t)fminf(fmaxf(v, -60000.f), 60000.f);
}

__device__ __forceinline__ half2_t h2shfl_xor(half2_t v, int mask) {
    int i = __builtin_bit_cast(int, v);
    i = __shfl_xor(i, mask);
    return __builtin_bit_cast(half2_t, i);
}

// ---------------- phase A: bin edges + pack fp16 ew (coalesced staging) ----------------
__global__ __launch_bounds__(256) void k_binA(
    const int* __restrict__ dst, const int* __restrict__ src,
    const float4* __restrict__ ew4,
    int* __restrict__ binCnt, int4* __restrict__ staged, int E, int nbins) {
    __shared__ int cnt[256], base[256], cur[256];
    int t = threadIdx.x;
    cnt[t] = 0;
    cur[t] = 0;
    __syncthreads();
    int e0 = blockIdx.x * 8192;
#pragma unroll 4
    for (int i = 0; i < 32; ++i) {
        int e = e0 + i * 256 + t;
        if (e < E) atomicAdd(&cnt[dst[e] >> 9], 1);
    }
    __syncthreads();
    if (t < nbins && cnt[t] > 0) base[t] = atomicAdd(&binCnt[t], cnt[t]);
    __syncthreads();
#pragma unroll 4
    for (int i = 0; i < 32; ++i) {
        int e = e0 + i * 256 + t;
        if (e < E) {
            int d = dst[e];
            int b = d >> 9;
            int j = base[b] + atomicAdd(&cur[b], 1);
            if (j < BIN_CAP) {
                float4 w = ew4[e];   // coalesced here (e sequential)
                half2_t lo = {(half_t)w.x, (half_t)w.y};
                half2_t hi = {(half_t)w.z, (half_t)w.w};
                staged[(size_t)b * BIN_CAP + j] =
                    make_int4(src[e], d & (NPB - 1),
                              __builtin_bit_cast(int, lo),
                              __builtin_bit_cast(int, hi));
            }
        }
    }
}

// ---------------- bin-count exclusive scan (nbins <= 256) ----------------
__global__ void k_scanN(const int* __restrict__ binCnt, int* __restrict__ binStart,
                        int* __restrict__ row_start, int nbins, int n, int E) {
    __shared__ int sh[256];
    int t = threadIdx.x;
    int v = (t < nbins) ? binCnt[t] : 0;
    sh[t] = v;
    __syncthreads();
    for (int s = 1; s < 256; s <<= 1) {
        int u = (t >= s) ? sh[t - s] : 0;
        __syncthreads();
        sh[t] += u;
        __syncthreads();
    }
    if (t < nbins) binStart[t] = sh[t] - v;
    if (t == 0) row_start[n] = E;
}

// ---------------- phase B: per-bin CSR; stats via per-node walk of sew ----------------
__global__ __launch_bounds__(512) void k_binB(
    const int* __restrict__ binCnt, const int* __restrict__ binStart,
    const int4* __restrict__ staged, const float* __restrict__ x,
    int* __restrict__ row_start, int* __restrict__ snbr, int2* __restrict__ sew,
    half_t* __restrict__ reps, int n) {
    __shared__ int deg[NPB], cur[NPB], rsl[NPB];
    int t = threadIdx.x;
    int bin = blockIdx.x;
    int cntE = min(binCnt[bin], BIN_CAP);
    int pbase = binStart[bin];
    const int4* st = staged + (size_t)bin * BIN_CAP;

    deg[t] = 0;
    cur[t] = 0;
    __syncthreads();

    // pass 1: degree count only (1 LDS atomic/edge)
    for (int i = t; i < cntE; i += 512)
        atomicAdd(&deg[st[i].y], 1);
    __syncthreads();

    int own = deg[t];
    for (int s = 1; s < NPB; s <<= 1) {   // inclusive Hillis-Steele scan
        int u = (t >= s) ? deg[t - s] : 0;
        __syncthreads();
        deg[t] += u;
        __syncthreads();
    }
    int excl = deg[t] - own;
    rsl[t] = pbase + excl;
    int node = bin * NPB + t;
    if (node < n) row_start[node] = pbase + excl;
    __syncthreads();

    // pass 2: scatter snbr + packed ew (1 LDS atomic/edge)
    for (int i = t; i < cntE; i += 512) {
        int4 v = st[i];
        int p = rsl[v.y] + atomicAdd(&cur[v.y], 1);
        snbr[p] = v.x;
        sew[p] = make_int2(v.z, v.w);
    }
    __syncthreads();   // sew visible block-wide (same-block L2)

    // pass 3: per-node stats via sequential walk (L2-hot window, no atomics)
    if (node < n) {
        int base = rsl[t];
        float s0 = 0.f, s1 = 0.f, s2 = 0.f, s3 = 0.f;
        half2_t mxlo = {(half_t)-65504.f, (half_t)-65504.f};
        half2_t mxhi = mxlo;
        half2_t mnlo = {(half_t)65504.f, (half_t)65504.f};
        half2_t mnhi = mnlo;
#pragma unroll 2
        for (int k = 0; k < own; ++k) {
            int2 e = sew[base + k];
            half2_t lo = __builtin_bit_cast(half2_t, e.x);
            half2_t hi = __builtin_bit_cast(half2_t, e.y);
            s0 += (float)lo[0];
            s1 += (float)lo[1];
            s2 += (float)hi[0];
            s3 += (float)hi[1];
            mxlo = __builtin_elementwise_max(mxlo, lo);
            mxhi = __builtin_elementwise_max(mxhi, hi);
            mnlo = __builtin_elementwise_min(mnlo, lo);
            mnhi = __builtin_elementwise_min(mnhi, hi);
        }
        float cnt = fmaxf((float)own, 1.0f);
        float rc = __builtin_amdgcn_rcpf(cnt);
        float mx0, mx1, mx2, mx3, mn0, mn1, mn2, mn3;
        if (own == 0) {
            mx0 = mx1 = mx2 = mx3 = -FLT_MAX;
            mn0 = mn1 = mn2 = mn3 = FLT_MAX;
        } else {
            mx0 = (float)mxlo[0]; mx1 = (float)mxlo[1];
            mx2 = (float)mxhi[0]; mx3 = (float)mxhi[1];
            mn0 = (float)mnlo[0]; mn1 = (float)mnlo[1];
            mn2 = (float)mnhi[0]; mn3 = (float)mnhi[1];
        }
        const float4* x4 = reinterpret_cast<const float4*>(x);
        float4 x0 = x4[node * 2 + 0], x1 = x4[node * 2 + 1];
        half_t* o = &reps[(size_t)node * 32];
        half8 c0 = {cvt_clamp(x0.x), cvt_clamp(x0.y), cvt_clamp(x0.z), cvt_clamp(x0.w),
                    cvt_clamp(x1.x), cvt_clamp(x1.y), cvt_clamp(x1.z), cvt_clamp(x1.w)};
        half8 c1 = {cvt_clamp(s0 * rc), cvt_clamp(s1 * rc), cvt_clamp(s2 * rc), cvt_clamp(s3 * rc),
                    cvt_clamp(mx0), cvt_clamp(mx1), cvt_clamp(mx2), cvt_clamp(mx3)};
        half8 c2 = {cvt_clamp(mn0), cvt_clamp(mn1), cvt_clamp(mn2), cvt_clamp(mn3),
                    cvt_clamp(s0), cvt_clamp(s1), cvt_clamp(s2), cvt_clamp(s3)};
        half8 c3 = {(half_t)0.f, (half_t)0.f, (half_t)0.f, (half_t)0.f,
                    (half_t)0.f, (half_t)0.f, (half_t)0.f, (half_t)0.f};
        *(half8*)&o[0] = c0;
        *(half8*)&o[8] = c1;
        *(half8*)&o[16] = c2;
        *(half8*)&o[24] = c3;
    }
}

// ---------------- weight prep: fp32 [k][n] -> fp16 [n][k] ----------------
__global__ void k_wprep(const float* __restrict__ Wu1, const float* __restrict__ Wu2,
                        const float* __restrict__ Wu3, half_t* __restrict__ Wt1,
                        half_t* __restrict__ Wt2, half_t* __restrict__ Wt3) {
    int i = blockIdx.x * 256 + threadIdx.x;
    if (i < 32768) {
        int nrow = i >> 7, k = i & 127;
        Wt1[i] = (half_t)Wu1[k * 256 + nrow];
    } else if (i < 65536) {
        int j = i - 32768;
        int nrow = j >> 8, k = j & 255;
        Wt2[j] = (half_t)Wu2[k * 128 + nrow];
    } else if (i < 69632) {
        int j = i - 65536;
        int nrow = j >> 7, k = j & 127;
        Wt3[j] = (half_t)Wu3[k * 32 + nrow];
    }
}

// ---------------- fused iter: LDS-idx gather + split-K MFMA MLP + l2norm ----------------
// nlist == nullptr: node = node0 + local slot (contiguous tile, sIdx staging).
// nlist != nullptr: node = nlist[node0 + slot] (sparse list; direct snbr reads).
#define MFMA16(a, b, c) __builtin_amdgcn_mfma_f32_16x16x32_f16((a), (b), (c), 0, 0, 0)

__global__ __launch_bounds__(512, 6) void k_mlp(
    const half_t* __restrict__ reps_in,
    const int* __restrict__ row_start, const int* __restrict__ snbr,
    const int* __restrict__ nlist, int nlen,
    const half_t* __restrict__ Wt1, const half_t* __restrict__ Wt2,
    const half_t* __restrict__ Wt3,
    const float* __restrict__ bu1, const float* __restrict__ bu2,
    const float* __restrict__ bu3,
    half_t* __restrict__ reps_out, int n) {
    __shared__ half_t sH[64 * 136];     // H[64][128]; later h2[64][128]
    __shared__ half_t sh1c[64 * 136];   // idx stage, then h1 chunk [64][128]
    __shared__ int sDeg[64], sPerm[64], sNode[64];
    int* sIdx = (int*)sh1c;             // 4352 int slots

    const int tid = threadIdx.x;
    const int w   = tid >> 6;
    const int l15 = tid & 15;
    const int lk  = (tid & 63) >> 4;
    const int node0 = blockIdx.x * 64;

    // ---- node table + degrees ----
    if (tid < 64) {
        int node;
        if (nlist) {
            int li = node0 + tid;
            node = (li < nlen) ? nlist[li] : -1;
        } else {
            node = node0 + tid;
        }
        if ((unsigned)node >= (unsigned)n) node = -1;
        sNode[tid] = node;
        sDeg[tid] = (node >= 0) ? (row_start[node + 1] - row_start[node]) : 0;
    }
    // ---- idx stage (identity path only): contiguous CSR -> coalesced burst ----
    const int nodeEnd = min(node0 + 64, n);
    int d0blk = 0;
    bool lds_ok = false;
    if (!nlist && node0 < n) {
        d0blk = row_start[node0];
        int ecnt = row_start[nodeEnd] - d0blk;
        lds_ok = (ecnt <= IDXCAP);
        if (lds_ok) {
            for (int i = tid; i < ecnt; i += 512)
                sIdx[i] = __builtin_nontemporal_load(&snbr[d0blk + i]);
        }
    }
    __syncthreads();
    // rank nodes by degree (desc, index tie-break) -> bijective perm
    if (tid < 64) {
        int dg = sDeg[tid];
        int rank = 0;
#pragma unroll
        for (int j = 0; j < 64; ++j) {
            int dj = sDeg[j];
            rank += (dj > dg) || (dj == dg && j < tid);
        }
        sPerm[rank] = tid;
    }
    __syncthreads();

    // ---- gather: 32 subgroups of 16 lanes; lane=(nb,ch); 16 edges/iter ----
    {
        const int sg = tid >> 4;
        const int l  = tid & 15;
        const int nb = l >> 2;
        const int ch = l & 3;

        for (int i = 0; i < 2; ++i) {
            int nl = sPerm[i * 32 + sg];
            int node = sNode[nl];
            float s[8];
            half2_t mx2[4], mn2[4];
#pragma unroll
            for (int f = 0; f < 8; ++f) s[f] = 0.f;
#pragma unroll
            for (int f = 0; f < 4; ++f) {
                mx2[f] = (half2_t){(half_t)-65504.f, (half_t)-65504.f};
                mn2[f] = (half2_t){(half_t)65504.f, (half_t)65504.f};
            }
            int d0 = 0, d1 = 0;
            if (node >= 0) { d0 = row_start[node]; d1 = row_start[node + 1]; }

            for (int e = d0; e < d1; e += 16) {
                int e0 = e + nb, e1 = e + 4 + nb, e2 = e + 8 + nb, e3 = e + 12 + nb;
                float m0 = (e0 < d1) ? 1.f : 0.f;
                float m1 = (e1 < d1) ? 1.f : 0.f;
                float m2 = (e2 < d1) ? 1.f : 0.f;
                float m3 = (e3 < d1) ? 1.f : 0.f;
                int ii0, ii1, ii2, ii3;
                if (lds_ok) {
                    ii0 = sIdx[min(e0, d1 - 1) - d0blk];
                    ii1 = sIdx[min(e1, d1 - 1) - d0blk];
                    ii2 = sIdx[min(e2, d1 - 1) - d0blk];
                    ii3 = sIdx[min(e3, d1 - 1) - d0blk];
                } else {
                    ii0 = snbr[min(e0, d1 - 1)];
                    ii1 = snbr[min(e1, d1 - 1)];
                    ii2 = snbr[min(e2, d1 - 1)];
                    ii3 = snbr[min(e3, d1 - 1)];
                }
                half8 r0 = *(const half8*)&reps_in[(size_t)ii0 * 32 + ch * 8];
                half8 r1 = *(const half8*)&reps_in[(size_t)ii1 * 32 + ch * 8];
                half8 r2 = *(const half8*)&reps_in[(size_t)ii2 * 32 + ch * 8];
                half8 r3 = *(const half8*)&reps_in[(size_t)ii3 * 32 + ch * 8];
#pragma unroll
                for (int f = 0; f < 4; ++f) {
                    half2_t a0 = (half2_t){r0[2 * f], r0[2 * f + 1]};
                    half2_t a1 = (half2_t){r1[2 * f], r1[2 * f + 1]};
                    half2_t a2 = (half2_t){r2[2 * f], r2[2 * f + 1]};
                    half2_t a3 = (half2_t){r3[2 * f], r3[2 * f + 1]};
                    mx2[f] = __builtin_elementwise_max(
                        __builtin_elementwise_max(mx2[f], a0),
                        __builtin_elementwise_max(a1,
                            __builtin_elementwise_max(a2, a3)));
                    mn2[f] = __builtin_elementwise_min(
                        __builtin_elementwise_min(mn2[f], a0),
                        __builtin_elementwise_min(a1,
                            __builtin_elementwise_min(a2, a3)));
                }
#pragma unroll
                for (int f = 0; f < 8; ++f) {
                    s[f] = fmaf((float)r0[f], m0, s[f]);
                    s[f] = fmaf((float)r1[f], m1, s[f]);
                    s[f] = fmaf((float)r2[f], m2, s[f]);
                    s[f] = fmaf((float)r3[f], m3, s[f]);
                }
            }
            // reduce across the 4 nb slots (xor strides 4, 8 inside subgroup)
#pragma unroll
            for (int f = 0; f < 8; ++f) {
                s[f] += __shfl_xor(s[f], 4);
                s[f] += __shfl_xor(s[f], 8);
            }
#pragma unroll
            for (int f = 0; f < 4; ++f) {
                mx2[f] = __builtin_elementwise_max(mx2[f], h2shfl_xor(mx2[f], 4));
                mx2[f] = __builtin_elementwise_max(mx2[f], h2shfl_xor(mx2[f], 8));
                mn2[f] = __builtin_elementwise_min(mn2[f], h2shfl_xor(mn2[f], 4));
                mn2[f] = __builtin_elementwise_min(mn2[f], h2shfl_xor(mn2[f], 8));
            }
            float cnt = fmaxf((float)(d1 - d0), 1.f);
            half8 o;
            if (nb == 0) {
                if (node >= 0) {
                    o = *(const half8*)&reps_in[(size_t)node * 32 + ch * 8];
                } else {
#pragma unroll
                    for (int f = 0; f < 8; ++f) o[f] = (half_t)0.f;
                }
            } else if (nb == 1) {
                float rc = __builtin_amdgcn_rcpf(cnt);
#pragma unroll
                for (int f = 0; f < 8; ++f) o[f] = cvt_clamp(s[f] * rc);
            } else if (nb == 2) {
#pragma unroll
                for (int f = 0; f < 4; ++f) {
                    o[2 * f]     = cvt_clamp((float)mx2[f][0]);
                    o[2 * f + 1] = cvt_clamp((float)mx2[f][1]);
                }
            } else {
#pragma unroll
                for (int f = 0; f < 4; ++f) {
                    o[2 * f]     = cvt_clamp((float)mn2[f][0]);
                    o[2 * f + 1] = cvt_clamp((float)mn2[f][1]);
                }
            }
            *(half8*)&sH[nl * 136 + l * 8] = o;
        }
    }
    __syncthreads();   // gather done; sIdx dead -> sh1c reusable

    // ---- split-K: 2 chunks of {GEMM1 128 cols -> GEMM2 partial} ----
    f32x4 acc2[4] = {{0.f, 0.f, 0.f, 0.f}, {0.f, 0.f, 0.f, 0.f},
                     {0.f, 0.f, 0.f, 0.f}, {0.f, 0.f, 0.f, 0.f}};
#pragma unroll
    for (int c = 0; c < 2; ++c) {
        // GEMM1 chunk c: wave w owns h1 cols [c*128 + w*16, +16)
        {
            half8 a[4];
#pragma unroll
            for (int ks = 0; ks < 4; ++ks)
                a[ks] = *(const half8*)&Wt1[(c * 128 + w * 16 + l15) * 128 + ks * 32 + lk * 8];
            f32x4 bv = *(const f32x4*)&bu1[c * 128 + w * 16 + lk * 4];
#pragma unroll
            for (int nt = 0; nt < 4; ++nt) {
                const half_t* hrow = &sH[(nt * 16 + l15) * 136 + lk * 8];
                half8 b0 = *(const half8*)&hrow[0];
                half8 b1 = *(const half8*)&hrow[32];
                half8 b2 = *(const half8*)&hrow[64];
                half8 b3 = *(const half8*)&hrow[96];
                f32x4 acc = {0.f, 0.f, 0.f, 0.f};
                acc = MFMA16(a[0], b0, acc);
                acc = MFMA16(a[1], b1, acc);
                acc = MFMA16(a[2], b2, acc);
                acc = MFMA16(a[3], b3, acc);
                half4_t o;
#pragma unroll
                for (int r = 0; r < 4; ++r)
                    o[r] = (half_t)fast_tanh(acc[r] + bv[r]);
                *(half4_t*)&sh1c[(nt * 16 + l15) * 136 + w * 16 + lk * 4] = o;
            }
        }
        __syncthreads();   // h1 chunk ready
        // GEMM2 partial: k in [c*128, c*128+128)
        {
            half8 a[4];
#pragma unroll
            for (int ks = 0; ks < 4; ++ks)
                a[ks] = *(const half8*)&Wt2[(w * 16 + l15) * 256 + c * 128 + ks * 32 + lk * 8];
#pragma unroll
            for (int nt = 0; nt < 4; ++nt) {
#pragma unroll
                for (int ks = 0; ks < 4; ++ks) {
                    half8 b = *(const half8*)&sh1c[(nt * 16 + l15) * 136 + ks * 32 + lk * 8];
                    acc2[nt] = MFMA16(a[ks], b, acc2[nt]);
                }
            }
        }
        __syncthreads();   // chunk reads done before overwrite / sH overlay
    }

    // ---- h2 = tanh(acc2 + b2) -> overlay into sH (dead after GEMM1) ----
    {
        f32x4 bv = *(const f32x4*)&bu2[w * 16 + lk * 4];
#pragma unroll
        for (int nt = 0; nt < 4; ++nt) {
            half4_t o;
#pragma unroll
            for (int r = 0; r < 4; ++r)
                o[r] = (half_t)fast_tanh(acc2[nt][r] + bv[r]);
            *(half4_t*)&sH[(nt * 16 + l15) * 136 + w * 16 + lk * 4] = o;
        }
    }
    __syncthreads();

    // ---- GEMM3 + l2norm: waves 0..3, wave w owns slots [w*16,(w+1)*16) ----
    if (w < 4) {
        half8 a0[4], a1[4], b[4];
#pragma unroll
        for (int ks = 0; ks < 4; ++ks) {
            a0[ks] = *(const half8*)&Wt3[l15 * 128 + ks * 32 + lk * 8];
            a1[ks] = *(const half8*)&Wt3[(16 + l15) * 128 + ks * 32 + lk * 8];
            b[ks]  = *(const half8*)&sH[(w * 16 + l15) * 136 + ks * 32 + lk * 8];
        }
        f32x4 acc0 = {0.f, 0.f, 0.f, 0.f}, acc1 = {0.f, 0.f, 0.f, 0.f};
#pragma unroll
        for (int ks = 0; ks < 4; ++ks) {
            acc0 = MFMA16(a0[ks], b[ks], acc0);
            acc1 = MFMA16(a1[ks], b[ks], acc1);
        }
        f32x4 bv0 = *(const f32x4*)&bu3[lk * 4];
        f32x4 bv1 = *(const f32x4*)&bu3[16 + lk * 4];
        float v0[4], v1[4];
        float ss = 0.f;
#pragma unroll
        for (int r = 0; r < 4; ++r) {
            v0[r] = fast_tanh(acc0[r] + bv0[r]);
            v1[r] = fast_tanh(acc1[r] + bv1[r]);
            ss += v0[r] * v0[r] + v1[r] * v1[r];
        }
        ss += __shfl_xor(ss, 16);
        ss += __shfl_xor(ss, 32);
        float sc = rsqrtf(fmaxf(ss, 1e-12f));
        int node = sNode[w * 16 + l15];
        if (node >= 0) {
            half4_t o0, o1;
#pragma unroll
            for (int r = 0; r < 4; ++r) {
                o0[r] = (half_t)(v0[r] * sc);
                o1[r] = (half_t)(v1[r] * sc);
            }
            *(half4_t*)&reps_out[(size_t)node * 32 + lk * 4] = o0;
            *(half4_t*)&reps_out[(size_t)node * 32 + 16 + lk * 4] = o1;
        }
    }
}

// ---------------- readout: gather generators (nan->0), 32->64->32->1 ----------------
__global__ __launch_bounds__(256) void k_readout(
    const half_t* __restrict__ reps, const int* __restrict__ gen,
    const float* __restrict__ Wr1, const float* __restrict__ br1,
    const float* __restrict__ Wr2, const float* __restrict__ br2,
    const float* __restrict__ Wr3, const float* __restrict__ br3,
    float* __restrict__ out, int ngen) {
    __shared__ float sW1[32 * 64];
    __shared__ float sW2[64 * 32];
    __shared__ float sb1[64];
    __shared__ float sb2[32];
    __shared__ float sW3r[32];
    __shared__ float sb3;
    int tid = threadIdx.x;
    for (int i = tid; i < 2048; i += 256) sW1[i] = Wr1[i];
    for (int i = tid; i < 2048; i += 256) sW2[i] = Wr2[i];
    if (tid < 64) sb1[tid] = br1[tid];
    if (tid < 32) sb2[tid] = br2[tid];
    if (tid < 32) sW3r[tid] = Wr3[tid];
    if (tid == 0) sb3 = br3[0];
    __syncthreads();
    int ig = blockIdx.x * 256 + tid;
    if (ig >= ngen) return;
    int node = gen[ig];
    float g[32];
#pragma unroll
    for (int q = 0; q < 4; ++q) {
        half8 v = *(const half8*)&reps[(size_t)node * 32 + q * 8];
#pragma unroll
        for (int r = 0; r < 8; ++r) {
            float f = (float)v[r];
            g[q * 8 + r] = (f != f) ? 0.f : f;
        }
    }
    float a[64];
#pragma unroll
    for (int o = 0; o < 64; ++o) {
        float acc = sb1[o];
#pragma unroll
        for (int k = 0; k < 32; ++k) acc = fmaf(g[k], sW1[k * 64 + o], acc);
        a[o] = fast_tanh(acc);
    }
    float b[32];
#pragma unroll
    for (int o = 0; o < 32; ++o) {
        float acc = sb2[o];
#pragma unroll
        for (int k = 0; k < 64; ++k) acc = fmaf(a[k], sW2[k * 32 + o], acc);
        b[o] = fast_tanh(acc);
    }
    float acc = sb3;
#pragma unroll
    for (int k = 0; k < 32; ++k) acc = fmaf(b[k], sW3r[k], acc);
    out[ig] = acc;
}

extern "C" void kernel_launch(void* const* d_in, const int* in_sizes, int n_in,
                              void* d_out, int out_size, void* d_ws, size_t ws_size,
                              hipStream_t stream) {
    const float* x   = (const float*)d_in[0];
    const float* ew  = (const float*)d_in[1];
    const float* Wu1 = (const float*)d_in[2];
    const float* bu1 = (const float*)d_in[3];
    const float* Wu2 = (const float*)d_in[4];
    const float* bu2 = (const float*)d_in[5];
    const float* Wu3 = (const float*)d_in[6];
    const float* bu3 = (const float*)d_in[7];
    const float* Wr1 = (const float*)d_in[8];
    const float* br1 = (const float*)d_in[9];
    const float* Wr2 = (const float*)d_in[10];
    const float* br2 = (const float*)d_in[11];
    const float* Wr3 = (const float*)d_in[12];
    const float* br3 = (const float*)d_in[13];
    const int* edges = (const int*)d_in[14];
    const int* gen   = (const int*)d_in[15];

    const int n    = in_sizes[0] / 8;
    const int E    = in_sizes[1] / 4;
    const int ngen = in_sizes[15];
    const int* dst = edges;      // node_idx (segment ids)
    const int* src = edges + E;  // nbr_idx (gather source)
    float* out = (float*)d_out;

    const int nblk  = (n + 63) / 64;
    const int npad  = nblk * 64;
    const int nbins = (n + NPB - 1) / NPB;

    // workspace layout (256B aligned slabs)
    char* ws = (char*)d_ws;
    size_t off = 0;
    auto alloc = [&](size_t bytes) -> char* {
        char* p = ws + off;
        off = (off + bytes + 255) & ~(size_t)255;
        return p;
    };
    int* row_start = (int*)alloc((size_t)(n + 1) * 4);
    int* binCnt    = (int*)alloc(256 * 4);
    int* binStart  = (int*)alloc(256 * 4);
    int* snbr      = (int*)alloc((size_t)E * 4);
    int2* sew      = (int2*)alloc((size_t)E * 8);   // CSR-ordered packed fp16 ew
    half_t* repsA  = (half_t*)alloc((size_t)npad * 32 * 2);
    half_t* repsB  = (half_t*)alloc((size_t)npad * 32 * 2);
    half_t* Wt1    = (half_t*)alloc(32768 * 2);
    half_t* Wt2    = (half_t*)alloc(32768 * 2);
    half_t* Wt3    = (half_t*)alloc(4096 * 2);
    int4* staged   = (int4*)alloc((size_t)nbins * BIN_CAP * 16);   // CSR build only

    // ---- CSR build (binned) + stats + reps ----
    hipMemsetAsync(binCnt, 0, 256 * 4, stream);
    int nblkA = (E + 8191) / 8192;
    k_binA<<<nblkA, 256, 0, stream>>>(dst, src, (const float4*)ew, binCnt, staged, E, nbins);
    k_scanN<<<1, 256, 0, stream>>>(binCnt, binStart, row_start, nbins, n, E);
    k_binB<<<nbins, 512, 0, stream>>>(binCnt, binStart, staged, x,
                                      row_start, snbr, sew, repsA, n);
    k_wprep<<<272, 256, 0, stream>>>(Wu1, Wu2, Wu3, Wt1, Wt2, Wt3);

    // it1, it2: full sweeps (identity mapping, sIdx staging)
    k_mlp<<<nblk, 512, 0, stream>>>(repsA, row_start, snbr, nullptr, 0,
                                    Wt1, Wt2, Wt3, bu1, bu2, bu3, repsB, n);
    k_mlp<<<nblk, 512, 0, stream>>>(repsB, row_start, snbr, nullptr, 0,
                                    Wt1, Wt2, Wt3, bu1, bu2, bu3, repsA, n);
    // it3: generator nodes only (readout consumes nothing else)
    int nblk3 = (ngen + 63) / 64;
    k_mlp<<<nblk3, 512, 0, stream>>>(repsA, row_start, snbr, gen, ngen,
                                     Wt1, Wt2, Wt3, bu1, bu2, bu3, repsB, n);

    k_readout<<<(ngen + 255) / 256, 256, 0, stream>>>(repsB, gen, Wr1, br1, Wr2, br2,
                                                      Wr3, br3, out, ngen);
}

// Round 17
// 261.711 us; speedup vs baseline: 1.1314x; 1.0003x over previous
//
#include <hip/hip_runtime.h>
#include <cfloat>
#include <cmath>

// ---------------------------------------------------------------------------
// GNN message passing — fp16 MFMA, round 17.
//  R17 changes (k_mlp gather micro, doubles as VALU-vs-latency ablation):
//   1. fp32 sum accumulators packed as float2 -> v_pk_fma_f32 (8 fma/row ->
//      4 pk_fma/row, ~20% of gather VALU). Bit-identical fp32 arithmetic.
//   2. Own-row read hoisted above the edge loop (exec-masked on nb==0 lanes)
//      so its ~400cy latency hides under the gather loop.
//  If k_mlp moves <2us, gather VALU is fully latency-hidden and this
//  decomposition is at its structural floor.
//  Everything else identical to r16 (64-node tile confirmed optimal; binned
//  CSR w/ packed fp16 ew; binB sequential-walk stats; it3 gen-only).
// MFMA mapping (verified r3-r16): D=A*B, A=W^T[nout][k], B=H[node][k]; D:
// col=lane&15=node, row=(lane>>4)*4+reg=nout.
// ---------------------------------------------------------------------------

typedef _Float16 half_t;
typedef _Float16 half8 __attribute__((ext_vector_type(8)));
typedef _Float16 half4_t __attribute__((ext_vector_type(4)));
typedef _Float16 half2_t __attribute__((ext_vector_type(2)));
typedef float f32x4 __attribute__((ext_vector_type(4)));
typedef float f32x2 __attribute__((ext_vector_type(2)));

#define NPB 512       // nodes per bin (power of 2: bin = dst>>9)
#define BIN_CAP 9216  // slots per bin; mean 8163, sd ~90 -> +11.7 sigma
#define IDXCAP 4352   // LDS idx slots per k_mlp block (mean 1024)

__device__ __forceinline__ float fast_tanh(float x) {
    float e = __builtin_amdgcn_exp2f(x * 2.8853900817779268f);
    return 1.0f - 2.0f * __builtin_amdgcn_rcpf(1.0f + e);
}

__device__ __forceinline__ half_t cvt_clamp(float v) {
    return (half_t)fminf(fmaxf(v, -60000.f), 60000.f);
}

__device__ __forceinline__ half2_t h2shfl_xor(half2_t v, int mask) {
    int i = __builtin_bit_cast(int, v);
    i = __shfl_xor(i, mask);
    return __builtin_bit_cast(half2_t, i);
}

// ---------------- phase A: bin edges + pack fp16 ew (coalesced staging) ----------------
__global__ __launch_bounds__(256) void k_binA(
    const int* __restrict__ dst, const int* __restrict__ src,
    const float4* __restrict__ ew4,
    int* __restrict__ binCnt, int4* __restrict__ staged, int E, int nbins) {
    __shared__ int cnt[256], base[256], cur[256];
    int t = threadIdx.x;
    cnt[t] = 0;
    cur[t] = 0;
    __syncthreads();
    int e0 = blockIdx.x * 8192;
#pragma unroll 4
    for (int i = 0; i < 32; ++i) {
        int e = e0 + i * 256 + t;
        if (e < E) atomicAdd(&cnt[dst[e] >> 9], 1);
    }
    __syncthreads();
    if (t < nbins && cnt[t] > 0) base[t] = atomicAdd(&binCnt[t], cnt[t]);
    __syncthreads();
#pragma unroll 4
    for (int i = 0; i < 32; ++i) {
        int e = e0 + i * 256 + t;
        if (e < E) {
            int d = dst[e];
            int b = d >> 9;
            int j = base[b] + atomicAdd(&cur[b], 1);
            if (j < BIN_CAP) {
                float4 w = ew4[e];   // coalesced here (e sequential)
                half2_t lo = {(half_t)w.x, (half_t)w.y};
                half2_t hi = {(half_t)w.z, (half_t)w.w};
                staged[(size_t)b * BIN_CAP + j] =
                    make_int4(src[e], d & (NPB - 1),
                              __builtin_bit_cast(int, lo),
                              __builtin_bit_cast(int, hi));
            }
        }
    }
}

// ---------------- bin-count exclusive scan (nbins <= 256) ----------------
__global__ void k_scanN(const int* __restrict__ binCnt, int* __restrict__ binStart,
                        int* __restrict__ row_start, int nbins, int n, int E) {
    __shared__ int sh[256];
    int t = threadIdx.x;
    int v = (t < nbins) ? binCnt[t] : 0;
    sh[t] = v;
    __syncthreads();
    for (int s = 1; s < 256; s <<= 1) {
        int u = (t >= s) ? sh[t - s] : 0;
        __syncthreads();
        sh[t] += u;
        __syncthreads();
    }
    if (t < nbins) binStart[t] = sh[t] - v;
    if (t == 0) row_start[n] = E;
}

// ---------------- phase B: per-bin CSR; stats via per-node walk of sew ----------------
__global__ __launch_bounds__(512) void k_binB(
    const int* __restrict__ binCnt, const int* __restrict__ binStart,
    const int4* __restrict__ staged, const float* __restrict__ x,
    int* __restrict__ row_start, int* __restrict__ snbr, int2* __restrict__ sew,
    half_t* __restrict__ reps, int n) {
    __shared__ int deg[NPB], cur[NPB], rsl[NPB];
    int t = threadIdx.x;
    int bin = blockIdx.x;
    int cntE = min(binCnt[bin], BIN_CAP);
    int pbase = binStart[bin];
    const int4* st = staged + (size_t)bin * BIN_CAP;

    deg[t] = 0;
    cur[t] = 0;
    __syncthreads();

    // pass 1: degree count only (1 LDS atomic/edge)
    for (int i = t; i < cntE; i += 512)
        atomicAdd(&deg[st[i].y], 1);
    __syncthreads();

    int own = deg[t];
    for (int s = 1; s < NPB; s <<= 1) {   // inclusive Hillis-Steele scan
        int u = (t >= s) ? deg[t - s] : 0;
        __syncthreads();
        deg[t] += u;
        __syncthreads();
    }
    int excl = deg[t] - own;
    rsl[t] = pbase + excl;
    int node = bin * NPB + t;
    if (node < n) row_start[node] = pbase + excl;
    __syncthreads();

    // pass 2: scatter snbr + packed ew (1 LDS atomic/edge)
    for (int i = t; i < cntE; i += 512) {
        int4 v = st[i];
        int p = rsl[v.y] + atomicAdd(&cur[v.y], 1);
        snbr[p] = v.x;
        sew[p] = make_int2(v.z, v.w);
    }
    __syncthreads();   // sew visible block-wide (same-block L2)

    // pass 3: per-node stats via sequential walk (L2-hot window, no atomics)
    if (node < n) {
        int base = rsl[t];
        float s0 = 0.f, s1 = 0.f, s2 = 0.f, s3 = 0.f;
        half2_t mxlo = {(half_t)-65504.f, (half_t)-65504.f};
        half2_t mxhi = mxlo;
        half2_t mnlo = {(half_t)65504.f, (half_t)65504.f};
        half2_t mnhi = mnlo;
#pragma unroll 2
        for (int k = 0; k < own; ++k) {
            int2 e = sew[base + k];
            half2_t lo = __builtin_bit_cast(half2_t, e.x);
            half2_t hi = __builtin_bit_cast(half2_t, e.y);
            s0 += (float)lo[0];
            s1 += (float)lo[1];
            s2 += (float)hi[0];
            s3 += (float)hi[1];
            mxlo = __builtin_elementwise_max(mxlo, lo);
            mxhi = __builtin_elementwise_max(mxhi, hi);
            mnlo = __builtin_elementwise_min(mnlo, lo);
            mnhi = __builtin_elementwise_min(mnhi, hi);
        }
        float cnt = fmaxf((float)own, 1.0f);
        float rc = __builtin_amdgcn_rcpf(cnt);
        float mx0, mx1, mx2, mx3, mn0, mn1, mn2, mn3;
        if (own == 0) {
            mx0 = mx1 = mx2 = mx3 = -FLT_MAX;
            mn0 = mn1 = mn2 = mn3 = FLT_MAX;
        } else {
            mx0 = (float)mxlo[0]; mx1 = (float)mxlo[1];
            mx2 = (float)mxhi[0]; mx3 = (float)mxhi[1];
            mn0 = (float)mnlo[0]; mn1 = (float)mnlo[1];
            mn2 = (float)mnhi[0]; mn3 = (float)mnhi[1];
        }
        const float4* x4 = reinterpret_cast<const float4*>(x);
        float4 x0 = x4[node * 2 + 0], x1 = x4[node * 2 + 1];
        half_t* o = &reps[(size_t)node * 32];
        half8 c0 = {cvt_clamp(x0.x), cvt_clamp(x0.y), cvt_clamp(x0.z), cvt_clamp(x0.w),
                    cvt_clamp(x1.x), cvt_clamp(x1.y), cvt_clamp(x1.z), cvt_clamp(x1.w)};
        half8 c1 = {cvt_clamp(s0 * rc), cvt_clamp(s1 * rc), cvt_clamp(s2 * rc), cvt_clamp(s3 * rc),
                    cvt_clamp(mx0), cvt_clamp(mx1), cvt_clamp(mx2), cvt_clamp(mx3)};
        half8 c2 = {cvt_clamp(mn0), cvt_clamp(mn1), cvt_clamp(mn2), cvt_clamp(mn3),
                    cvt_clamp(s0), cvt_clamp(s1), cvt_clamp(s2), cvt_clamp(s3)};
        half8 c3 = {(half_t)0.f, (half_t)0.f, (half_t)0.f, (half_t)0.f,
                    (half_t)0.f, (half_t)0.f, (half_t)0.f, (half_t)0.f};
        *(half8*)&o[0] = c0;
        *(half8*)&o[8] = c1;
        *(half8*)&o[16] = c2;
        *(half8*)&o[24] = c3;
    }
}

// ---------------- weight prep: fp32 [k][n] -> fp16 [n][k] ----------------
__global__ void k_wprep(const float* __restrict__ Wu1, const float* __restrict__ Wu2,
                        const float* __restrict__ Wu3, half_t* __restrict__ Wt1,
                        half_t* __restrict__ Wt2, half_t* __restrict__ Wt3) {
    int i = blockIdx.x * 256 + threadIdx.x;
    if (i < 32768) {
        int nrow = i >> 7, k = i & 127;
        Wt1[i] = (half_t)Wu1[k * 256 + nrow];
    } else if (i < 65536) {
        int j = i - 32768;
        int nrow = j >> 8, k = j & 255;
        Wt2[j] = (half_t)Wu2[k * 128 + nrow];
    } else if (i < 69632) {
        int j = i - 65536;
        int nrow = j >> 7, k = j & 127;
        Wt3[j] = (half_t)Wu3[k * 32 + nrow];
    }
}

// ---------------- fused iter: LDS-idx gather + split-K MFMA MLP + l2norm ----------------
// nlist == nullptr: node = node0 + local slot (contiguous tile, sIdx staging).
// nlist != nullptr: node = nlist[node0 + slot] (sparse list; direct snbr reads).
#define MFMA16(a, b, c) __builtin_amdgcn_mfma_f32_16x16x32_f16((a), (b), (c), 0, 0, 0)

__global__ __launch_bounds__(512, 6) void k_mlp(
    const half_t* __restrict__ reps_in,
    const int* __restrict__ row_start, const int* __restrict__ snbr,
    const int* __restrict__ nlist, int nlen,
    const half_t* __restrict__ Wt1, const half_t* __restrict__ Wt2,
    const half_t* __restrict__ Wt3,
    const float* __restrict__ bu1, const float* __restrict__ bu2,
    const float* __restrict__ bu3,
    half_t* __restrict__ reps_out, int n) {
    __shared__ half_t sH[64 * 136];     // H[64][128]; later h2[64][128]
    __shared__ half_t sh1c[64 * 136];   // idx stage, then h1 chunk [64][128]
    __shared__ int sDeg[64], sPerm[64], sNode[64];
    int* sIdx = (int*)sh1c;             // 4352 int slots

    const int tid = threadIdx.x;
    const int w   = tid >> 6;
    const int l15 = tid & 15;
    const int lk  = (tid & 63) >> 4;
    const int node0 = blockIdx.x * 64;

    // ---- node table + degrees ----
    if (tid < 64) {
        int node;
        if (nlist) {
            int li = node0 + tid;
            node = (li < nlen) ? nlist[li] : -1;
        } else {
            node = node0 + tid;
        }
        if ((unsigned)node >= (unsigned)n) node = -1;
        sNode[tid] = node;
        sDeg[tid] = (node >= 0) ? (row_start[node + 1] - row_start[node]) : 0;
    }
    // ---- idx stage (identity path only): contiguous CSR -> coalesced burst ----
    const int nodeEnd = min(node0 + 64, n);
    int d0blk = 0;
    bool lds_ok = false;
    if (!nlist && node0 < n) {
        d0blk = row_start[node0];
        int ecnt = row_start[nodeEnd] - d0blk;
        lds_ok = (ecnt <= IDXCAP);
        if (lds_ok) {
            for (int i = tid; i < ecnt; i += 512)
                sIdx[i] = __builtin_nontemporal_load(&snbr[d0blk + i]);
        }
    }
    __syncthreads();
    // rank nodes by degree (desc, index tie-break) -> bijective perm
    if (tid < 64) {
        int dg = sDeg[tid];
        int rank = 0;
#pragma unroll
        for (int j = 0; j < 64; ++j) {
            int dj = sDeg[j];
            rank += (dj > dg) || (dj == dg && j < tid);
        }
        sPerm[rank] = tid;
    }
    __syncthreads();

    // ---- gather: 32 subgroups of 16 lanes; lane=(nb,ch); 16 edges/iter ----
    {
        const int sg = tid >> 4;
        const int l  = tid & 15;
        const int nb = l >> 2;
        const int ch = l & 3;

        for (int i = 0; i < 2; ++i) {
            int nl = sPerm[i * 32 + sg];
            int node = sNode[nl];
            // own-row prefetch (nb==0 lanes; latency hides under edge loop)
            half8 ownrow;
            if (nb == 0 && node >= 0)
                ownrow = *(const half8*)&reps_in[(size_t)node * 32 + ch * 8];
            f32x2 s2[4];
            half2_t mx2[4], mn2[4];
#pragma unroll
            for (int f = 0; f < 4; ++f) {
                s2[f] = (f32x2){0.f, 0.f};
                mx2[f] = (half2_t){(half_t)-65504.f, (half_t)-65504.f};
                mn2[f] = (half2_t){(half_t)65504.f, (half_t)65504.f};
            }
            int d0 = 0, d1 = 0;
            if (node >= 0) { d0 = row_start[node]; d1 = row_start[node + 1]; }

            for (int e = d0; e < d1; e += 16) {
                int e0 = e + nb, e1 = e + 4 + nb, e2 = e + 8 + nb, e3 = e + 12 + nb;
                f32x2 m0 = (e0 < d1) ? (f32x2){1.f, 1.f} : (f32x2){0.f, 0.f};
                f32x2 m1 = (e1 < d1) ? (f32x2){1.f, 1.f} : (f32x2){0.f, 0.f};
                f32x2 m2 = (e2 < d1) ? (f32x2){1.f, 1.f} : (f32x2){0.f, 0.f};
                f32x2 m3 = (e3 < d1) ? (f32x2){1.f, 1.f} : (f32x2){0.f, 0.f};
                int ii0, ii1, ii2, ii3;
                if (lds_ok) {
                    ii0 = sIdx[min(e0, d1 - 1) - d0blk];
                    ii1 = sIdx[min(e1, d1 - 1) - d0blk];
                    ii2 = sIdx[min(e2, d1 - 1) - d0blk];
                    ii3 = sIdx[min(e3, d1 - 1) - d0blk];
                } else {
                    ii0 = snbr[min(e0, d1 - 1)];
                    ii1 = snbr[min(e1, d1 - 1)];
                    ii2 = snbr[min(e2, d1 - 1)];
                    ii3 = snbr[min(e3, d1 - 1)];
                }
                half8 r0 = *(const half8*)&reps_in[(size_t)ii0 * 32 + ch * 8];
                half8 r1 = *(const half8*)&reps_in[(size_t)ii1 * 32 + ch * 8];
                half8 r2 = *(const half8*)&reps_in[(size_t)ii2 * 32 + ch * 8];
                half8 r3 = *(const half8*)&reps_in[(size_t)ii3 * 32 + ch * 8];
#pragma unroll
                for (int f = 0; f < 4; ++f) {
                    half2_t a0 = (half2_t){r0[2 * f], r0[2 * f + 1]};
                    half2_t a1 = (half2_t){r1[2 * f], r1[2 * f + 1]};
                    half2_t a2 = (half2_t){r2[2 * f], r2[2 * f + 1]};
                    half2_t a3 = (half2_t){r3[2 * f], r3[2 * f + 1]};
                    mx2[f] = __builtin_elementwise_max(
                        __builtin_elementwise_max(mx2[f], a0),
                        __builtin_elementwise_max(a1,
                            __builtin_elementwise_max(a2, a3)));
                    mn2[f] = __builtin_elementwise_min(
                        __builtin_elementwise_min(mn2[f], a0),
                        __builtin_elementwise_min(a1,
                            __builtin_elementwise_min(a2, a3)));
                    // packed fp32 sums: v_pk_fma_f32 (bit-identical fp32 fma)
                    f32x2 v0 = {(float)a0[0], (float)a0[1]};
                    f32x2 v1 = {(float)a1[0], (float)a1[1]};
                    f32x2 v2 = {(float)a2[0], (float)a2[1]};
                    f32x2 v3 = {(float)a3[0], (float)a3[1]};
                    s2[f] = v0 * m0 + s2[f];
                    s2[f] = v1 * m1 + s2[f];
                    s2[f] = v2 * m2 + s2[f];
                    s2[f] = v3 * m3 + s2[f];
                }
            }
            // reduce across the 4 nb slots (xor strides 4, 8 inside subgroup)
#pragma unroll
            for (int f = 0; f < 4; ++f) {
                s2[f][0] += __shfl_xor(s2[f][0], 4);
                s2[f][1] += __shfl_xor(s2[f][1], 4);
                s2[f][0] += __shfl_xor(s2[f][0], 8);
                s2[f][1] += __shfl_xor(s2[f][1], 8);
                mx2[f] = __builtin_elementwise_max(mx2[f], h2shfl_xor(mx2[f], 4));
                mx2[f] = __builtin_elementwise_max(mx2[f], h2shfl_xor(mx2[f], 8));
                mn2[f] = __builtin_elementwise_min(mn2[f], h2shfl_xor(mn2[f], 4));
                mn2[f] = __builtin_elementwise_min(mn2[f], h2shfl_xor(mn2[f], 8));
            }
            float cnt = fmaxf((float)(d1 - d0), 1.f);
            half8 o;
            if (nb == 0) {
                if (node >= 0) {
                    o = ownrow;
                } else {
#pragma unroll
                    for (int f = 0; f < 8; ++f) o[f] = (half_t)0.f;
                }
            } else if (nb == 1) {
                float rc = __builtin_amdgcn_rcpf(cnt);
#pragma unroll
                for (int f = 0; f < 4; ++f) {
                    o[2 * f]     = cvt_clamp(s2[f][0] * rc);
                    o[2 * f + 1] = cvt_clamp(s2[f][1] * rc);
                }
            } else if (nb == 2) {
#pragma unroll
                for (int f = 0; f < 4; ++f) {
                    o[2 * f]     = cvt_clamp((float)mx2[f][0]);
                    o[2 * f + 1] = cvt_clamp((float)mx2[f][1]);
                }
            } else {
#pragma unroll
                for (int f = 0; f < 4; ++f) {
                    o[2 * f]     = cvt_clamp((float)mn2[f][0]);
                    o[2 * f + 1] = cvt_clamp((float)mn2[f][1]);
                }
            }
            *(half8*)&sH[nl * 136 + l * 8] = o;
        }
    }
    __syncthreads();   // gather done; sIdx dead -> sh1c reusable

    // ---- split-K: 2 chunks of {GEMM1 128 cols -> GEMM2 partial} ----
    f32x4 acc2[4] = {{0.f, 0.f, 0.f, 0.f}, {0.f, 0.f, 0.f, 0.f},
                     {0.f, 0.f, 0.f, 0.f}, {0.f, 0.f, 0.f, 0.f}};
#pragma unroll
    for (int c = 0; c < 2; ++c) {
        // GEMM1 chunk c: wave w owns h1 cols [c*128 + w*16, +16)
        {
            half8 a[4];
#pragma unroll
            for (int ks = 0; ks < 4; ++ks)
                a[ks] = *(const half8*)&Wt1[(c * 128 + w * 16 + l15) * 128 + ks * 32 + lk * 8];
            f32x4 bv = *(const f32x4*)&bu1[c * 128 + w * 16 + lk * 4];
#pragma unroll
            for (int nt = 0; nt < 4; ++nt) {
                const half_t* hrow = &sH[(nt * 16 + l15) * 136 + lk * 8];
                half8 b0 = *(const half8*)&hrow[0];
                half8 b1 = *(const half8*)&hrow[32];
                half8 b2 = *(const half8*)&hrow[64];
                half8 b3 = *(const half8*)&hrow[96];
                f32x4 acc = {0.f, 0.f, 0.f, 0.f};
                acc = MFMA16(a[0], b0, acc);
                acc = MFMA16(a[1], b1, acc);
                acc = MFMA16(a[2], b2, acc);
                acc = MFMA16(a[3], b3, acc);
                half4_t o;
#pragma unroll
                for (int r = 0; r < 4; ++r)
                    o[r] = (half_t)fast_tanh(acc[r] + bv[r]);
                *(half4_t*)&sh1c[(nt * 16 + l15) * 136 + w * 16 + lk * 4] = o;
            }
        }
        __syncthreads();   // h1 chunk ready
        // GEMM2 partial: k in [c*128, c*128+128)
        {
            half8 a[4];
#pragma unroll
            for (int ks = 0; ks < 4; ++ks)
                a[ks] = *(const half8*)&Wt2[(w * 16 + l15) * 256 + c * 128 + ks * 32 + lk * 8];
#pragma unroll
            for (int nt = 0; nt < 4; ++nt) {
#pragma unroll
                for (int ks = 0; ks < 4; ++ks) {
                    half8 b = *(const half8*)&sh1c[(nt * 16 + l15) * 136 + ks * 32 + lk * 8];
                    acc2[nt] = MFMA16(a[ks], b, acc2[nt]);
                }
            }
        }
        __syncthreads();   // chunk reads done before overwrite / sH overlay
    }

    // ---- h2 = tanh(acc2 + b2) -> overlay into sH (dead after GEMM1) ----
    {
        f32x4 bv = *(const f32x4*)&bu2[w * 16 + lk * 4];
#pragma unroll
        for (int nt = 0; nt < 4; ++nt) {
            half4_t o;
#pragma unroll
            for (int r = 0; r < 4; ++r)
                o[r] = (half_t)fast_tanh(acc2[nt][r] + bv[r]);
            *(half4_t*)&sH[(nt * 16 + l15) * 136 + w * 16 + lk * 4] = o;
        }
    }
    __syncthreads();

    // ---- GEMM3 + l2norm: waves 0..3, wave w owns slots [w*16,(w+1)*16) ----
    if (w < 4) {
        half8 a0[4], a1[4], b[4];
#pragma unroll
        for (int ks = 0; ks < 4; ++ks) {
            a0[ks] = *(const half8*)&Wt3[l15 * 128 + ks * 32 + lk * 8];
            a1[ks] = *(const half8*)&Wt3[(16 + l15) * 128 + ks * 32 + lk * 8];
            b[ks]  = *(const half8*)&sH[(w * 16 + l15) * 136 + ks * 32 + lk * 8];
        }
        f32x4 acc0 = {0.f, 0.f, 0.f, 0.f}, acc1 = {0.f, 0.f, 0.f, 0.f};
#pragma unroll
        for (int ks = 0; ks < 4; ++ks) {
            acc0 = MFMA16(a0[ks], b[ks], acc0);
            acc1 = MFMA16(a1[ks], b[ks], acc1);
        }
        f32x4 bv0 = *(const f32x4*)&bu3[lk * 4];
        f32x4 bv1 = *(const f32x4*)&bu3[16 + lk * 4];
        float v0[4], v1[4];
        float ss = 0.f;
#pragma unroll
        for (int r = 0; r < 4; ++r) {
            v0[r] = fast_tanh(acc0[r] + bv0[r]);
            v1[r] = fast_tanh(acc1[r] + bv1[r]);
            ss += v0[r] * v0[r] + v1[r] * v1[r];
        }
        ss += __shfl_xor(ss, 16);
        ss += __shfl_xor(ss, 32);
        float sc = rsqrtf(fmaxf(ss, 1e-12f));
        int node = sNode[w * 16 + l15];
        if (node >= 0) {
            half4_t o0, o1;
#pragma unroll
            for (int r = 0; r < 4; ++r) {
                o0[r] = (half_t)(v0[r] * sc);
                o1[r] = (half_t)(v1[r] * sc);
            }
            *(half4_t*)&reps_out[(size_t)node * 32 + lk * 4] = o0;
            *(half4_t*)&reps_out[(size_t)node * 32 + 16 + lk * 4] = o1;
        }
    }
}

// ---------------- readout: gather generators (nan->0), 32->64->32->1 ----------------
__global__ __launch_bounds__(256) void k_readout(
    const half_t* __restrict__ reps, const int* __restrict__ gen,
    const float* __restrict__ Wr1, const float* __restrict__ br1,
    const float* __restrict__ Wr2, const float* __restrict__ br2,
    const float* __restrict__ Wr3, const float* __restrict__ br3,
    float* __restrict__ out, int ngen) {
    __shared__ float sW1[32 * 64];
    __shared__ float sW2[64 * 32];
    __shared__ float sb1[64];
    __shared__ float sb2[32];
    __shared__ float sW3r[32];
    __shared__ float sb3;
    int tid = threadIdx.x;
    for (int i = tid; i < 2048; i += 256) sW1[i] = Wr1[i];
    for (int i = tid; i < 2048; i += 256) sW2[i] = Wr2[i];
    if (tid < 64) sb1[tid] = br1[tid];
    if (tid < 32) sb2[tid] = br2[tid];
    if (tid < 32) sW3r[tid] = Wr3[tid];
    if (tid == 0) sb3 = br3[0];
    __syncthreads();
    int ig = blockIdx.x * 256 + tid;
    if (ig >= ngen) return;
    int node = gen[ig];
    float g[32];
#pragma unroll
    for (int q = 0; q < 4; ++q) {
        half8 v = *(const half8*)&reps[(size_t)node * 32 + q * 8];
#pragma unroll
        for (int r = 0; r < 8; ++r) {
            float f = (float)v[r];
            g[q * 8 + r] = (f != f) ? 0.f : f;
        }
    }
    float a[64];
#pragma unroll
    for (int o = 0; o < 64; ++o) {
        float acc = sb1[o];
#pragma unroll
        for (int k = 0; k < 32; ++k) acc = fmaf(g[k], sW1[k * 64 + o], acc);
        a[o] = fast_tanh(acc);
    }
    float b[32];
#pragma unroll
    for (int o = 0; o < 32; ++o) {
        float acc = sb2[o];
#pragma unroll
        for (int k = 0; k < 64; ++k) acc = fmaf(a[k], sW2[k * 32 + o], acc);
        b[o] = fast_tanh(acc);
    }
    float acc = sb3;
#pragma unroll
    for (int k = 0; k < 32; ++k) acc = fmaf(b[k], sW3r[k], acc);
    out[ig] = acc;
}

extern "C" void kernel_launch(void* const* d_in, const int* in_sizes, int n_in,
                              void* d_out, int out_size, void* d_ws, size_t ws_size,
                              hipStream_t stream) {
    const float* x   = (const float*)d_in[0];
    const float* ew  = (const float*)d_in[1];
    const float* Wu1 = (const float*)d_in[2];
    const float* bu1 = (const float*)d_in[3];
    const float* Wu2 = (const float*)d_in[4];
    const float* bu2 = (const float*)d_in[5];
    const float* Wu3 = (const float*)d_in[6];
    const float* bu3 = (const float*)d_in[7];
    const float* Wr1 = (const float*)d_in[8];
    const float* br1 = (const float*)d_in[9];
    const float* Wr2 = (const float*)d_in[10];
    const float* br2 = (const float*)d_in[11];
    const float* Wr3 = (const float*)d_in[12];
    const float* br3 = (const float*)d_in[13];
    const int* edges = (const int*)d_in[14];
    const int* gen   = (const int*)d_in[15];

    const int n    = in_sizes[0] / 8;
    const int E    = in_sizes[1] / 4;
    const int ngen = in_sizes[15];
    const int* dst = edges;      // node_idx (segment ids)
    const int* src = edges + E;  // nbr_idx (gather source)
    float* out = (float*)d_out;

    const int nblk  = (n + 63) / 64;
    const int npad  = nblk * 64;
    const int nbins = (n + NPB - 1) / NPB;

    // workspace layout (256B aligned slabs)
    char* ws = (char*)d_ws;
    size_t off = 0;
    auto alloc = [&](size_t bytes) -> char* {
        char* p = ws + off;
        off = (off + bytes + 255) & ~(size_t)255;
        return p;
    };
    int* row_start = (int*)alloc((size_t)(n + 1) * 4);
    int* binCnt    = (int*)alloc(256 * 4);
    int* binStart  = (int*)alloc(256 * 4);
    int* snbr      = (int*)alloc((size_t)E * 4);
    int2* sew      = (int2*)alloc((size_t)E * 8);   // CSR-ordered packed fp16 ew
    half_t* repsA  = (half_t*)alloc((size_t)npad * 32 * 2);
    half_t* repsB  = (half_t*)alloc((size_t)npad * 32 * 2);
    half_t* Wt1    = (half_t*)alloc(32768 * 2);
    half_t* Wt2    = (half_t*)alloc(32768 * 2);
    half_t* Wt3    = (half_t*)alloc(4096 * 2);
    int4* staged   = (int4*)alloc((size_t)nbins * BIN_CAP * 16);   // CSR build only

    // ---- CSR build (binned) + stats + reps ----
    hipMemsetAsync(binCnt, 0, 256 * 4, stream);
    int nblkA = (E + 8191) / 8192;
    k_binA<<<nblkA, 256, 0, stream>>>(dst, src, (const float4*)ew, binCnt, staged, E, nbins);
    k_scanN<<<1, 256, 0, stream>>>(binCnt, binStart, row_start, nbins, n, E);
    k_binB<<<nbins, 512, 0, stream>>>(binCnt, binStart, staged, x,
                                      row_start, snbr, sew, repsA, n);
    k_wprep<<<272, 256, 0, stream>>>(Wu1, Wu2, Wu3, Wt1, Wt2, Wt3);

    // it1, it2: full sweeps (identity mapping, sIdx staging)
    k_mlp<<<nblk, 512, 0, stream>>>(repsA, row_start, snbr, nullptr, 0,
                                    Wt1, Wt2, Wt3, bu1, bu2, bu3, repsB, n);
    k_mlp<<<nblk, 512, 0, stream>>>(repsB, row_start, snbr, nullptr, 0,
                                    Wt1, Wt2, Wt3, bu1, bu2, bu3, repsA, n);
    // it3: generator nodes only (readout consumes nothing else)
    int nblk3 = (ngen + 63) / 64;
    k_mlp<<<nblk3, 512, 0, stream>>>(repsA, row_start, snbr, gen, ngen,
                                     Wt1, Wt2, Wt3, bu1, bu2, bu3, repsB, n);

    k_readout<<<(ngen + 255) / 256, 256, 0, stream>>>(repsB, gen, Wr1, br1, Wr2, br2,
                                                      Wr3, br3, out, ngen);
}

// Round 18
// 248.935 us; speedup vs baseline: 1.1895x; 1.0513x over previous
//
#include <hip/hip_runtime.h>
#include <cfloat>
#include <cmath>

// ---------------------------------------------------------------------------
// GNN message passing — fp16 MFMA, round 18.
//  R17 post-mortem: gather VALU cut + prefetch = exactly 0 change -> k_mlp
//  (71.5us) is latency-floor-bound for this decomposition; stop touching it.
//  R18 targets the never-profiled ~110us CSR region (all dispatches < 71us,
//  invisible in top-5; binA/binB run only 196 blocks = sub-1/CU):
//   1. binA 8192 -> 4096 edges/block (391 blocks, >=1.5/CU).
//   2. binB 512 -> 1024 threads (16 waves; halves strided-pass rounds).
//   3. scanN folded into binB (per-block 256-entry LDS scan of binCnt);
//      kernel + launch gap + binStart buffer deleted.
//  If total moves <5us, the region is gap/readout-dominated -> declare
//  practical roofline next round.
// MFMA mapping (verified r3-r17): D=A*B, A=W^T[nout][k], B=H[node][k]; D:
// col=lane&15=node, row=(lane>>4)*4+reg=nout.
// ---------------------------------------------------------------------------

typedef _Float16 half_t;
typedef _Float16 half8 __attribute__((ext_vector_type(8)));
typedef _Float16 half4_t __attribute__((ext_vector_type(4)));
typedef _Float16 half2_t __attribute__((ext_vector_type(2)));
typedef float f32x4 __attribute__((ext_vector_type(4)));
typedef float f32x2 __attribute__((ext_vector_type(2)));

#define NPB 512       // nodes per bin (power of 2: bin = dst>>9)
#define BIN_CAP 9216  // slots per bin; mean 8163, sd ~90 -> +11.7 sigma
#define IDXCAP 4352   // LDS idx slots per k_mlp block (mean 1024)

__device__ __forceinline__ float fast_tanh(float x) {
    float e = __builtin_amdgcn_exp2f(x * 2.8853900817779268f);
    return 1.0f - 2.0f * __builtin_amdgcn_rcpf(1.0f + e);
}

__device__ __forceinline__ half_t cvt_clamp(float v) {
    return (half_t)fminf(fmaxf(v, -60000.f), 60000.f);
}

__device__ __forceinline__ half2_t h2shfl_xor(half2_t v, int mask) {
    int i = __builtin_bit_cast(int, v);
    i = __shfl_xor(i, mask);
    return __builtin_bit_cast(half2_t, i);
}

// ---------------- phase A: bin edges + pack fp16 ew (coalesced staging) ----------------
__global__ __launch_bounds__(256) void k_binA(
    const int* __restrict__ dst, const int* __restrict__ src,
    const float4* __restrict__ ew4,
    int* __restrict__ binCnt, int4* __restrict__ staged, int E, int nbins) {
    __shared__ int cnt[256], base[256], cur[256];
    int t = threadIdx.x;
    cnt[t] = 0;
    cur[t] = 0;
    __syncthreads();
    int e0 = blockIdx.x * 4096;   // r18: 4096/block -> 391 blocks
#pragma unroll 4
    for (int i = 0; i < 16; ++i) {
        int e = e0 + i * 256 + t;
        if (e < E) atomicAdd(&cnt[dst[e] >> 9], 1);
    }
    __syncthreads();
    if (t < nbins && cnt[t] > 0) base[t] = atomicAdd(&binCnt[t], cnt[t]);
    __syncthreads();
#pragma unroll 4
    for (int i = 0; i < 16; ++i) {
        int e = e0 + i * 256 + t;
        if (e < E) {
            int d = dst[e];
            int b = d >> 9;
            int j = base[b] + atomicAdd(&cur[b], 1);
            if (j < BIN_CAP) {
                float4 w = ew4[e];   // coalesced here (e sequential)
                half2_t lo = {(half_t)w.x, (half_t)w.y};
                half2_t hi = {(half_t)w.z, (half_t)w.w};
                staged[(size_t)b * BIN_CAP + j] =
                    make_int4(src[e], d & (NPB - 1),
                              __builtin_bit_cast(int, lo),
                              __builtin_bit_cast(int, hi));
            }
        }
    }
}

// ---------------- phase B: bin-scan + per-bin CSR + stats + reps ----------------
__global__ __launch_bounds__(1024) void k_binB(
    const int* __restrict__ binCnt,
    const int4* __restrict__ staged, const float* __restrict__ x,
    int* __restrict__ row_start, int* __restrict__ snbr, int2* __restrict__ sew,
    half_t* __restrict__ reps, int n, int E, int nbins) {
    __shared__ int deg[NPB], cur[NPB], rsl[NPB];
    __shared__ int sBC[256];
    int t = threadIdx.x;
    int bin = blockIdx.x;

    // inline exclusive scan of binCnt (replaces k_scanN)
    if (t < 256) sBC[t] = (t < nbins) ? binCnt[t] : 0;
    if (t < NPB) { deg[t] = 0; cur[t] = 0; }
    __syncthreads();
    for (int s = 1; s < 256; s <<= 1) {
        int u = (t < 256 && t >= s) ? sBC[t - s] : 0;
        __syncthreads();
        if (t < 256) sBC[t] += u;
        __syncthreads();
    }
    int pbase = (bin > 0) ? sBC[bin - 1] : 0;
    if (bin == 0 && t == 0) row_start[n] = E;

    int cntE = min(binCnt[bin], BIN_CAP);
    const int4* st = staged + (size_t)bin * BIN_CAP;

    // pass 1: degree count (1 LDS atomic/edge)
    for (int i = t; i < cntE; i += 1024)
        atomicAdd(&deg[st[i].y], 1);
    __syncthreads();

    int own = (t < NPB) ? deg[t] : 0;
    for (int s = 1; s < NPB; s <<= 1) {   // inclusive Hillis-Steele (t<512 active)
        int u = (t < NPB && t >= s) ? deg[t - s] : 0;
        __syncthreads();
        if (t < NPB) deg[t] += u;
        __syncthreads();
    }
    int node = bin * NPB + t;
    if (t < NPB) {
        int excl = deg[t] - own;
        rsl[t] = pbase + excl;
        if (node < n) row_start[node] = pbase + excl;
    }
    __syncthreads();

    // pass 2: scatter snbr + packed ew (1 LDS atomic/edge)
    for (int i = t; i < cntE; i += 1024) {
        int4 v = st[i];
        int p = rsl[v.y] + atomicAdd(&cur[v.y], 1);
        snbr[p] = v.x;
        sew[p] = make_int2(v.z, v.w);
    }
    __syncthreads();   // sew visible block-wide

    // pass 3: per-node stats via sequential walk (L2-hot window, no atomics)
    if (t < NPB && node < n) {
        int base = rsl[t];
        float s0 = 0.f, s1 = 0.f, s2 = 0.f, s3 = 0.f;
        half2_t mxlo = {(half_t)-65504.f, (half_t)-65504.f};
        half2_t mxhi = mxlo;
        half2_t mnlo = {(half_t)65504.f, (half_t)65504.f};
        half2_t mnhi = mnlo;
#pragma unroll 2
        for (int k = 0; k < own; ++k) {
            int2 e = sew[base + k];
            half2_t lo = __builtin_bit_cast(half2_t, e.x);
            half2_t hi = __builtin_bit_cast(half2_t, e.y);
            s0 += (float)lo[0];
            s1 += (float)lo[1];
            s2 += (float)hi[0];
            s3 += (float)hi[1];
            mxlo = __builtin_elementwise_max(mxlo, lo);
            mxhi = __builtin_elementwise_max(mxhi, hi);
            mnlo = __builtin_elementwise_min(mnlo, lo);
            mnhi = __builtin_elementwise_min(mnhi, hi);
        }
        float cnt = fmaxf((float)own, 1.0f);
        float rc = __builtin_amdgcn_rcpf(cnt);
        float mx0, mx1, mx2, mx3, mn0, mn1, mn2, mn3;
        if (own == 0) {
            mx0 = mx1 = mx2 = mx3 = -FLT_MAX;
            mn0 = mn1 = mn2 = mn3 = FLT_MAX;
        } else {
            mx0 = (float)mxlo[0]; mx1 = (float)mxlo[1];
            mx2 = (float)mxhi[0]; mx3 = (float)mxhi[1];
            mn0 = (float)mnlo[0]; mn1 = (float)mnlo[1];
            mn2 = (float)mnhi[0]; mn3 = (float)mnhi[1];
        }
        const float4* x4 = reinterpret_cast<const float4*>(x);
        float4 x0 = x4[node * 2 + 0], x1 = x4[node * 2 + 1];
        half_t* o = &reps[(size_t)node * 32];
        half8 c0 = {cvt_clamp(x0.x), cvt_clamp(x0.y), cvt_clamp(x0.z), cvt_clamp(x0.w),
                    cvt_clamp(x1.x), cvt_clamp(x1.y), cvt_clamp(x1.z), cvt_clamp(x1.w)};
        half8 c1 = {cvt_clamp(s0 * rc), cvt_clamp(s1 * rc), cvt_clamp(s2 * rc), cvt_clamp(s3 * rc),
                    cvt_clamp(mx0), cvt_clamp(mx1), cvt_clamp(mx2), cvt_clamp(mx3)};
        half8 c2 = {cvt_clamp(mn0), cvt_clamp(mn1), cvt_clamp(mn2), cvt_clamp(mn3),
                    cvt_clamp(s0), cvt_clamp(s1), cvt_clamp(s2), cvt_clamp(s3)};
        half8 c3 = {(half_t)0.f, (half_t)0.f, (half_t)0.f, (half_t)0.f,
                    (half_t)0.f, (half_t)0.f, (half_t)0.f, (half_t)0.f};
        *(half8*)&o[0] = c0;
        *(half8*)&o[8] = c1;
        *(half8*)&o[16] = c2;
        *(half8*)&o[24] = c3;
    }
}

// ---------------- weight prep: fp32 [k][n] -> fp16 [n][k] ----------------
__global__ void k_wprep(const float* __restrict__ Wu1, const float* __restrict__ Wu2,
                        const float* __restrict__ Wu3, half_t* __restrict__ Wt1,
                        half_t* __restrict__ Wt2, half_t* __restrict__ Wt3) {
    int i = blockIdx.x * 256 + threadIdx.x;
    if (i < 32768) {
        int nrow = i >> 7, k = i & 127;
        Wt1[i] = (half_t)Wu1[k * 256 + nrow];
    } else if (i < 65536) {
        int j = i - 32768;
        int nrow = j >> 8, k = j & 255;
        Wt2[j] = (half_t)Wu2[k * 128 + nrow];
    } else if (i < 69632) {
        int j = i - 65536;
        int nrow = j >> 7, k = j & 127;
        Wt3[j] = (half_t)Wu3[k * 32 + nrow];
    }
}

// ---------------- fused iter: LDS-idx gather + split-K MFMA MLP + l2norm ----------------
// nlist == nullptr: node = node0 + local slot (contiguous tile, sIdx staging).
// nlist != nullptr: node = nlist[node0 + slot] (sparse list; direct snbr reads).
#define MFMA16(a, b, c) __builtin_amdgcn_mfma_f32_16x16x32_f16((a), (b), (c), 0, 0, 0)

__global__ __launch_bounds__(512, 6) void k_mlp(
    const half_t* __restrict__ reps_in,
    const int* __restrict__ row_start, const int* __restrict__ snbr,
    const int* __restrict__ nlist, int nlen,
    const half_t* __restrict__ Wt1, const half_t* __restrict__ Wt2,
    const half_t* __restrict__ Wt3,
    const float* __restrict__ bu1, const float* __restrict__ bu2,
    const float* __restrict__ bu3,
    half_t* __restrict__ reps_out, int n) {
    __shared__ half_t sH[64 * 136];     // H[64][128]; later h2[64][128]
    __shared__ half_t sh1c[64 * 136];   // idx stage, then h1 chunk [64][128]
    __shared__ int sDeg[64], sPerm[64], sNode[64];
    int* sIdx = (int*)sh1c;             // 4352 int slots

    const int tid = threadIdx.x;
    const int w   = tid >> 6;
    const int l15 = tid & 15;
    const int lk  = (tid & 63) >> 4;
    const int node0 = blockIdx.x * 64;

    // ---- node table + degrees ----
    if (tid < 64) {
        int node;
        if (nlist) {
            int li = node0 + tid;
            node = (li < nlen) ? nlist[li] : -1;
        } else {
            node = node0 + tid;
        }
        if ((unsigned)node >= (unsigned)n) node = -1;
        sNode[tid] = node;
        sDeg[tid] = (node >= 0) ? (row_start[node + 1] - row_start[node]) : 0;
    }
    // ---- idx stage (identity path only): contiguous CSR -> coalesced burst ----
    const int nodeEnd = min(node0 + 64, n);
    int d0blk = 0;
    bool lds_ok = false;
    if (!nlist && node0 < n) {
        d0blk = row_start[node0];
        int ecnt = row_start[nodeEnd] - d0blk;
        lds_ok = (ecnt <= IDXCAP);
        if (lds_ok) {
            for (int i = tid; i < ecnt; i += 512)
                sIdx[i] = __builtin_nontemporal_load(&snbr[d0blk + i]);
        }
    }
    __syncthreads();
    // rank nodes by degree (desc, index tie-break) -> bijective perm
    if (tid < 64) {
        int dg = sDeg[tid];
        int rank = 0;
#pragma unroll
        for (int j = 0; j < 64; ++j) {
            int dj = sDeg[j];
            rank += (dj > dg) || (dj == dg && j < tid);
        }
        sPerm[rank] = tid;
    }
    __syncthreads();

    // ---- gather: 32 subgroups of 16 lanes; lane=(nb,ch); 16 edges/iter ----
    {
        const int sg = tid >> 4;
        const int l  = tid & 15;
        const int nb = l >> 2;
        const int ch = l & 3;

        for (int i = 0; i < 2; ++i) {
            int nl = sPerm[i * 32 + sg];
            int node = sNode[nl];
            // own-row prefetch (nb==0 lanes; latency hides under edge loop)
            half8 ownrow;
            if (nb == 0 && node >= 0)
                ownrow = *(const half8*)&reps_in[(size_t)node * 32 + ch * 8];
            f32x2 s2[4];
            half2_t mx2[4], mn2[4];
#pragma unroll
            for (int f = 0; f < 4; ++f) {
                s2[f] = (f32x2){0.f, 0.f};
                mx2[f] = (half2_t){(half_t)-65504.f, (half_t)-65504.f};
                mn2[f] = (half2_t){(half_t)65504.f, (half_t)65504.f};
            }
            int d0 = 0, d1 = 0;
            if (node >= 0) { d0 = row_start[node]; d1 = row_start[node + 1]; }

            for (int e = d0; e < d1; e += 16) {
                int e0 = e + nb, e1 = e + 4 + nb, e2 = e + 8 + nb, e3 = e + 12 + nb;
                f32x2 m0 = (e0 < d1) ? (f32x2){1.f, 1.f} : (f32x2){0.f, 0.f};
                f32x2 m1 = (e1 < d1) ? (f32x2){1.f, 1.f} : (f32x2){0.f, 0.f};
                f32x2 m2 = (e2 < d1) ? (f32x2){1.f, 1.f} : (f32x2){0.f, 0.f};
                f32x2 m3 = (e3 < d1) ? (f32x2){1.f, 1.f} : (f32x2){0.f, 0.f};
                int ii0, ii1, ii2, ii3;
                if (lds_ok) {
                    ii0 = sIdx[min(e0, d1 - 1) - d0blk];
                    ii1 = sIdx[min(e1, d1 - 1) - d0blk];
                    ii2 = sIdx[min(e2, d1 - 1) - d0blk];
                    ii3 = sIdx[min(e3, d1 - 1) - d0blk];
                } else {
                    ii0 = snbr[min(e0, d1 - 1)];
                    ii1 = snbr[min(e1, d1 - 1)];
                    ii2 = snbr[min(e2, d1 - 1)];
                    ii3 = snbr[min(e3, d1 - 1)];
                }
                half8 r0 = *(const half8*)&reps_in[(size_t)ii0 * 32 + ch * 8];
                half8 r1 = *(const half8*)&reps_in[(size_t)ii1 * 32 + ch * 8];
                half8 r2 = *(const half8*)&reps_in[(size_t)ii2 * 32 + ch * 8];
                half8 r3 = *(const half8*)&reps_in[(size_t)ii3 * 32 + ch * 8];
#pragma unroll
                for (int f = 0; f < 4; ++f) {
                    half2_t a0 = (half2_t){r0[2 * f], r0[2 * f + 1]};
                    half2_t a1 = (half2_t){r1[2 * f], r1[2 * f + 1]};
                    half2_t a2 = (half2_t){r2[2 * f], r2[2 * f + 1]};
                    half2_t a3 = (half2_t){r3[2 * f], r3[2 * f + 1]};
                    mx2[f] = __builtin_elementwise_max(
                        __builtin_elementwise_max(mx2[f], a0),
                        __builtin_elementwise_max(a1,
                            __builtin_elementwise_max(a2, a3)));
                    mn2[f] = __builtin_elementwise_min(
                        __builtin_elementwise_min(mn2[f], a0),
                        __builtin_elementwise_min(a1,
                            __builtin_elementwise_min(a2, a3)));
                    f32x2 v0 = {(float)a0[0], (float)a0[1]};
                    f32x2 v1 = {(float)a1[0], (float)a1[1]};
                    f32x2 v2 = {(float)a2[0], (float)a2[1]};
                    f32x2 v3 = {(float)a3[0], (float)a3[1]};
                    s2[f] = v0 * m0 + s2[f];
                    s2[f] = v1 * m1 + s2[f];
                    s2[f] = v2 * m2 + s2[f];
                    s2[f] = v3 * m3 + s2[f];
                }
            }
            // reduce across the 4 nb slots (xor strides 4, 8 inside subgroup)
#pragma unroll
            for (int f = 0; f < 4; ++f) {
                s2[f][0] += __shfl_xor(s2[f][0], 4);
                s2[f][1] += __shfl_xor(s2[f][1], 4);
                s2[f][0] += __shfl_xor(s2[f][0], 8);
                s2[f][1] += __shfl_xor(s2[f][1], 8);
                mx2[f] = __builtin_elementwise_max(mx2[f], h2shfl_xor(mx2[f], 4));
                mx2[f] = __builtin_elementwise_max(mx2[f], h2shfl_xor(mx2[f], 8));
                mn2[f] = __builtin_elementwise_min(mn2[f], h2shfl_xor(mn2[f], 4));
                mn2[f] = __builtin_elementwise_min(mn2[f], h2shfl_xor(mn2[f], 8));
            }
            float cnt = fmaxf((float)(d1 - d0), 1.f);
            half8 o;
            if (nb == 0) {
                if (node >= 0) {
                    o = ownrow;
                } else {
#pragma unroll
                    for (int f = 0; f < 8; ++f) o[f] = (half_t)0.f;
                }
            } else if (nb == 1) {
                float rc = __builtin_amdgcn_rcpf(cnt);
#pragma unroll
                for (int f = 0; f < 4; ++f) {
                    o[2 * f]     = cvt_clamp(s2[f][0] * rc);
                    o[2 * f + 1] = cvt_clamp(s2[f][1] * rc);
                }
            } else if (nb == 2) {
#pragma unroll
                for (int f = 0; f < 4; ++f) {
                    o[2 * f]     = cvt_clamp((float)mx2[f][0]);
                    o[2 * f + 1] = cvt_clamp((float)mx2[f][1]);
                }
            } else {
#pragma unroll
                for (int f = 0; f < 4; ++f) {
                    o[2 * f]     = cvt_clamp((float)mn2[f][0]);
                    o[2 * f + 1] = cvt_clamp((float)mn2[f][1]);
                }
            }
            *(half8*)&sH[nl * 136 + l * 8] = o;
        }
    }
    __syncthreads();   // gather done; sIdx dead -> sh1c reusable

    // ---- split-K: 2 chunks of {GEMM1 128 cols -> GEMM2 partial} ----
    f32x4 acc2[4] = {{0.f, 0.f, 0.f, 0.f}, {0.f, 0.f, 0.f, 0.f},
                     {0.f, 0.f, 0.f, 0.f}, {0.f, 0.f, 0.f, 0.f}};
#pragma unroll
    for (int c = 0; c < 2; ++c) {
        // GEMM1 chunk c: wave w owns h1 cols [c*128 + w*16, +16)
        {
            half8 a[4];
#pragma unroll
            for (int ks = 0; ks < 4; ++ks)
                a[ks] = *(const half8*)&Wt1[(c * 128 + w * 16 + l15) * 128 + ks * 32 + lk * 8];
            f32x4 bv = *(const f32x4*)&bu1[c * 128 + w * 16 + lk * 4];
#pragma unroll
            for (int nt = 0; nt < 4; ++nt) {
                const half_t* hrow = &sH[(nt * 16 + l15) * 136 + lk * 8];
                half8 b0 = *(const half8*)&hrow[0];
                half8 b1 = *(const half8*)&hrow[32];
                half8 b2 = *(const half8*)&hrow[64];
                half8 b3 = *(const half8*)&hrow[96];
                f32x4 acc = {0.f, 0.f, 0.f, 0.f};
                acc = MFMA16(a[0], b0, acc);
                acc = MFMA16(a[1], b1, acc);
                acc = MFMA16(a[2], b2, acc);
                acc = MFMA16(a[3], b3, acc);
                half4_t o;
#pragma unroll
                for (int r = 0; r < 4; ++r)
                    o[r] = (half_t)fast_tanh(acc[r] + bv[r]);
                *(half4_t*)&sh1c[(nt * 16 + l15) * 136 + w * 16 + lk * 4] = o;
            }
        }
        __syncthreads();   // h1 chunk ready
        // GEMM2 partial: k in [c*128, c*128+128)
        {
            half8 a[4];
#pragma unroll
            for (int ks = 0; ks < 4; ++ks)
                a[ks] = *(const half8*)&Wt2[(w * 16 + l15) * 256 + c * 128 + ks * 32 + lk * 8];
#pragma unroll
            for (int nt = 0; nt < 4; ++nt) {
#pragma unroll
                for (int ks = 0; ks < 4; ++ks) {
                    half8 b = *(const half8*)&sh1c[(nt * 16 + l15) * 136 + ks * 32 + lk * 8];
                    acc2[nt] = MFMA16(a[ks], b, acc2[nt]);
                }
            }
        }
        __syncthreads();   // chunk reads done before overwrite / sH overlay
    }

    // ---- h2 = tanh(acc2 + b2) -> overlay into sH (dead after GEMM1) ----
    {
        f32x4 bv = *(const f32x4*)&bu2[w * 16 + lk * 4];
#pragma unroll
        for (int nt = 0; nt < 4; ++nt) {
            half4_t o;
#pragma unroll
            for (int r = 0; r < 4; ++r)
                o[r] = (half_t)fast_tanh(acc2[nt][r] + bv[r]);
            *(half4_t*)&sH[(nt * 16 + l15) * 136 + w * 16 + lk * 4] = o;
        }
    }
    __syncthreads();

    // ---- GEMM3 + l2norm: waves 0..3, wave w owns slots [w*16,(w+1)*16) ----
    if (w < 4) {
        half8 a0[4], a1[4], b[4];
#pragma unroll
        for (int ks = 0; ks < 4; ++ks) {
            a0[ks] = *(const half8*)&Wt3[l15 * 128 + ks * 32 + lk * 8];
            a1[ks] = *(const half8*)&Wt3[(16 + l15) * 128 + ks * 32 + lk * 8];
            b[ks]  = *(const half8*)&sH[(w * 16 + l15) * 136 + ks * 32 + lk * 8];
        }
        f32x4 acc0 = {0.f, 0.f, 0.f, 0.f}, acc1 = {0.f, 0.f, 0.f, 0.f};
#pragma unroll
        for (int ks = 0; ks < 4; ++ks) {
            acc0 = MFMA16(a0[ks], b[ks], acc0);
            acc1 = MFMA16(a1[ks], b[ks], acc1);
        }
        f32x4 bv0 = *(const f32x4*)&bu3[lk * 4];
        f32x4 bv1 = *(const f32x4*)&bu3[16 + lk * 4];
        float v0[4], v1[4];
        float ss = 0.f;
#pragma unroll
        for (int r = 0; r < 4; ++r) {
            v0[r] = fast_tanh(acc0[r] + bv0[r]);
            v1[r] = fast_tanh(acc1[r] + bv1[r]);
            ss += v0[r] * v0[r] + v1[r] * v1[r];
        }
        ss += __shfl_xor(ss, 16);
        ss += __shfl_xor(ss, 32);
        float sc = rsqrtf(fmaxf(ss, 1e-12f));
        int node = sNode[w * 16 + l15];
        if (node >= 0) {
            half4_t o0, o1;
#pragma unroll
            for (int r = 0; r < 4; ++r) {
                o0[r] = (half_t)(v0[r] * sc);
                o1[r] = (half_t)(v1[r] * sc);
            }
            *(half4_t*)&reps_out[(size_t)node * 32 + lk * 4] = o0;
            *(half4_t*)&reps_out[(size_t)node * 32 + 16 + lk * 4] = o1;
        }
    }
}

// ---------------- readout: gather generators (nan->0), 32->64->32->1 ----------------
__global__ __launch_bounds__(256) void k_readout(
    const half_t* __restrict__ reps, const int* __restrict__ gen,
    const float* __restrict__ Wr1, const float* __restrict__ br1,
    const float* __restrict__ Wr2, const float* __restrict__ br2,
    const float* __restrict__ Wr3, const float* __restrict__ br3,
    float* __restrict__ out, int ngen) {
    __shared__ float sW1[32 * 64];
    __shared__ float sW2[64 * 32];
    __shared__ float sb1[64];
    __shared__ float sb2[32];
    __shared__ float sW3r[32];
    __shared__ float sb3;
    int tid = threadIdx.x;
    for (int i = tid; i < 2048; i += 256) sW1[i] = Wr1[i];
    for (int i = tid; i < 2048; i += 256) sW2[i] = Wr2[i];
    if (tid < 64) sb1[tid] = br1[tid];
    if (tid < 32) sb2[tid] = br2[tid];
    if (tid < 32) sW3r[tid] = Wr3[tid];
    if (tid == 0) sb3 = br3[0];
    __syncthreads();
    int ig = blockIdx.x * 256 + tid;
    if (ig >= ngen) return;
    int node = gen[ig];
    float g[32];
#pragma unroll
    for (int q = 0; q < 4; ++q) {
        half8 v = *(const half8*)&reps[(size_t)node * 32 + q * 8];
#pragma unroll
        for (int r = 0; r < 8; ++r) {
            float f = (float)v[r];
            g[q * 8 + r] = (f != f) ? 0.f : f;
        }
    }
    float a[64];
#pragma unroll
    for (int o = 0; o < 64; ++o) {
        float acc = sb1[o];
#pragma unroll
        for (int k = 0; k < 32; ++k) acc = fmaf(g[k], sW1[k * 64 + o], acc);
        a[o] = fast_tanh(acc);
    }
    float b[32];
#pragma unroll
    for (int o = 0; o < 32; ++o) {
        float acc = sb2[o];
#pragma unroll
        for (int k = 0; k < 64; ++k) acc = fmaf(a[k], sW2[k * 32 + o], acc);
        b[o] = fast_tanh(acc);
    }
    float acc = sb3;
#pragma unroll
    for (int k = 0; k < 32; ++k) acc = fmaf(b[k], sW3r[k], acc);
    out[ig] = acc;
}

extern "C" void kernel_launch(void* const* d_in, const int* in_sizes, int n_in,
                              void* d_out, int out_size, void* d_ws, size_t ws_size,
                              hipStream_t stream) {
    const float* x   = (const float*)d_in[0];
    const float* ew  = (const float*)d_in[1];
    const float* Wu1 = (const float*)d_in[2];
    const float* bu1 = (const float*)d_in[3];
    const float* Wu2 = (const float*)d_in[4];
    const float* bu2 = (const float*)d_in[5];
    const float* Wu3 = (const float*)d_in[6];
    const float* bu3 = (const float*)d_in[7];
    const float* Wr1 = (const float*)d_in[8];
    const float* br1 = (const float*)d_in[9];
    const float* Wr2 = (const float*)d_in[10];
    const float* br2 = (const float*)d_in[11];
    const float* Wr3 = (const float*)d_in[12];
    const float* br3 = (const float*)d_in[13];
    const int* edges = (const int*)d_in[14];
    const int* gen   = (const int*)d_in[15];

    const int n    = in_sizes[0] / 8;
    const int E    = in_sizes[1] / 4;
    const int ngen = in_sizes[15];
    const int* dst = edges;      // node_idx (segment ids)
    const int* src = edges + E;  // nbr_idx (gather source)
    float* out = (float*)d_out;

    const int nblk  = (n + 63) / 64;
    const int npad  = nblk * 64;
    const int nbins = (n + NPB - 1) / NPB;

    // workspace layout (256B aligned slabs)
    char* ws = (char*)d_ws;
    size_t off = 0;
    auto alloc = [&](size_t bytes) -> char* {
        char* p = ws + off;
        off = (off + bytes + 255) & ~(size_t)255;
        return p;
    };
    int* row_start = (int*)alloc((size_t)(n + 1) * 4);
    int* binCnt    = (int*)alloc(256 * 4);
    int* snbr      = (int*)alloc((size_t)E * 4);
    int2* sew      = (int2*)alloc((size_t)E * 8);   // CSR-ordered packed fp16 ew
    half_t* repsA  = (half_t*)alloc((size_t)npad * 32 * 2);
    half_t* repsB  = (half_t*)alloc((size_t)npad * 32 * 2);
    half_t* Wt1    = (half_t*)alloc(32768 * 2);
    half_t* Wt2    = (half_t*)alloc(32768 * 2);
    half_t* Wt3    = (half_t*)alloc(4096 * 2);
    int4* staged   = (int4*)alloc((size_t)nbins * BIN_CAP * 16);   // CSR build only

    // ---- CSR build (binned) + stats + reps ----
    hipMemsetAsync(binCnt, 0, 256 * 4, stream);
    int nblkA = (E + 4095) / 4096;
    k_binA<<<nblkA, 256, 0, stream>>>(dst, src, (const float4*)ew, binCnt, staged, E, nbins);
    k_binB<<<nbins, 1024, 0, stream>>>(binCnt, staged, x,
                                       row_start, snbr, sew, repsA, n, E, nbins);
    k_wprep<<<272, 256, 0, stream>>>(Wu1, Wu2, Wu3, Wt1, Wt2, Wt3);

    // it1, it2: full sweeps (identity mapping, sIdx staging)
    k_mlp<<<nblk, 512, 0, stream>>>(repsA, row_start, snbr, nullptr, 0,
                                    Wt1, Wt2, Wt3, bu1, bu2, bu3, repsB, n);
    k_mlp<<<nblk, 512, 0, stream>>>(repsB, row_start, snbr, nullptr, 0,
                                    Wt1, Wt2, Wt3, bu1, bu2, bu3, repsA, n);
    // it3: generator nodes only (readout consumes nothing else)
    int nblk3 = (ngen + 63) / 64;
    k_mlp<<<nblk3, 512, 0, stream>>>(repsA, row_start, snbr, gen, ngen,
                                     Wt1, Wt2, Wt3, bu1, bu2, bu3, repsB, n);

    k_readout<<<(ngen + 255) / 256, 256, 0, stream>>>(repsB, gen, Wr1, br1, Wr2, br2,
                                                      Wr3, br3, out, ngen);
}